// Round 13
// baseline (2485.749 us; speedup 1.0000x reference)
//
#include <hip/hip_runtime.h>
#include <math.h>

typedef float f32x4 __attribute__((ext_vector_type(4)));
typedef short bf16x8 __attribute__((ext_vector_type(8)));
typedef unsigned int uint32;
#define DEV static __device__ __forceinline__

constexpr int B_ = 8, N_ = 30, T_ = 100, FIN = 4, H_ = 128;
constexpr int E_ = N_*(N_-1);          // 870
constexpr int NSEQ = B_*E_;            // 6960
constexpr int RN = B_*N_*T_;           // 24000 node rows
constexpr int RE = B_*E_*T_;           // 696000 edge rows
constexpr int ET = E_*T_;              // 87000
constexpr int NB_GRU = (NSEQ + 63)/64; // 109

DEV float eluf(float x){ return x > 0.f ? x : __expf(x) - 1.f; }
DEV float sigmoidf(float x){ return 1.f/(1.f + __expf(-x)); }
DEV float tanhfast(float x){
  float cx = fminf(fmaxf(x, -20.f), 20.f);
  float e = __expf(2.f*cx);
  return (e - 1.f)/(e + 1.f);
}
DEV float dot4(f32x4 a, f32x4 b){ return a[0]*b[0] + a[1]*b[1] + a[2]*b[2] + a[3]*b[3]; }

DEV float bf2f(unsigned short u){ return __uint_as_float(((uint32)u) << 16); }
DEV uint32 f2bf_bits(float f){ uint32 b = __float_as_uint(f); return (b + 0x7FFFu + ((b >> 16) & 1u)) >> 16; }
DEV uint32 pack2(float lo, float hi){ return f2bf_bits(lo) | (f2bf_bits(hi) << 16); }

// load 8 consecutive floats, round to 8 bf16
DEV bf16x8 cvt8(const float* __restrict__ p){
  f32x4 a = *(const f32x4*)p;
  f32x4 b = *(const f32x4*)(p+4);
  bf16x8 r;
  r[0]=(short)f2bf_bits(a[0]); r[1]=(short)f2bf_bits(a[1]);
  r[2]=(short)f2bf_bits(a[2]); r[3]=(short)f2bf_bits(a[3]);
  r[4]=(short)f2bf_bits(b[0]); r[5]=(short)f2bf_bits(b[1]);
  r[6]=(short)f2bf_bits(b[2]); r[7]=(short)f2bf_bits(b[3]);
  return r;
}
// same but element-wise scaled (BN fold)
DEV bf16x8 cvt8s(const float* __restrict__ p, const float* __restrict__ sc){
  bf16x8 r;
  #pragma unroll
  for (int e=0;e<8;++e) r[e] = (short)f2bf_bits(p[e]*sc[e]);
  return r;
}

// decompose edge row -> b, t, sender node, receiver node
DEV void edge_decomp(int row, int& b, int& t, int& sn, int& ir)
{
  b = row / ET;
  int rem = row - b*ET;
  int e   = rem / T_;
  t = rem - e*T_;
  ir = e / (N_-1);
  int j = e - ir*(N_-1);
  sn = j + (j >= ir ? 1 : 0);
}

// bijective XCD swizzle (m204)
DEV int xcd_swizzle(int orig, int nwg)
{
  int q = nwg >> 3, r = nwg & 7;
  int xcd = orig & 7, j = orig >> 3;
  return (xcd < r ? xcd*(q+1) : r*(q+1) + (xcd-r)*q) + j;
}

// ================= weight prep: fp32 -> bf16 (w21|w22|w41|w42) =================
__global__ __launch_bounds__(256)
void prep_weights(const float* __restrict__ w21, const float* __restrict__ w22,
                  const float* __restrict__ w41, const float* __restrict__ w42,
                  unsigned short* __restrict__ wbf)
{
  int idx = blockIdx.x*256 + threadIdx.x;
  if (idx >= 114688) return;
  float v;
  if (idx < 32768)      v = w21[idx];
  else if (idx < 49152) v = w22[idx - 32768];
  else if (idx < 98304) v = w41[idx - 49152];
  else                  v = w42[idx - 98304];
  wbf[idx] = (unsigned short)f2bf_bits(v);
}

// ================= simple fused 2-layer MLP (node-sized, fp32 out) =================
template<int MODE, int DIN>
__global__ __launch_bounds__(256)
void mlp_fused(const float* __restrict__ src,
               const float* __restrict__ w1, const float* __restrict__ b1,
               const float* __restrict__ w2, const float* __restrict__ b2,
               float* __restrict__ out)
{
  constexpr int KC  = (DIN < 32) ? DIN : 32;
  constexpr int NCH = DIN / KC;
  __shared__ float As[KC][68];
  __shared__ float Ws[32][132];
  __shared__ float Hs[128][68];

  const int tid  = threadIdx.x;
  const int row0 = blockIdx.x * 64;
  const int tx = tid & 15, ty = tid >> 4;
  const int c0 = tx*8, r0 = ty*4;

  float acc[4][8];
  #pragma unroll
  for (int j=0;j<4;++j){
    #pragma unroll
    for (int i=0;i<8;++i) acc[j][i]=0.f;
  }

  for (int ch = 0; ch < NCH; ++ch) {
    for (int idx = tid; idx < 64*KC; idx += 256) {
      int r = idx / KC, k = idx % KC;
      As[k][r] = src[(size_t)(row0 + r)*DIN + ch*KC + k];
    }
    for (int idx = tid; idx < 128*KC; idx += 256) {
      int o = idx / KC, k = idx % KC;
      Ws[k][o] = w1[o*DIN + ch*KC + k];
    }
    __syncthreads();
    #pragma unroll
    for (int k = 0; k < KC; ++k) {
      f32x4 a  = *(const f32x4*)&As[k][r0];
      f32x4 wA = *(const f32x4*)&Ws[k][c0];
      f32x4 wB = *(const f32x4*)&Ws[k][c0+4];
      #pragma unroll
      for (int j=0;j<4;++j){
        #pragma unroll
        for (int i=0;i<4;++i){
          acc[j][i]   += a[j]*wA[i];
          acc[j][4+i] += a[j]*wB[i];
        }
      }
    }
    __syncthreads();
  }
  {
    #pragma unroll
    for (int i=0;i<8;++i){
      float bb = b1[c0+i];
      #pragma unroll
      for (int j=0;j<4;++j)
        Hs[c0+i][r0+j] = eluf(acc[j][i] + bb);
    }
  }
  __syncthreads();

  #pragma unroll
  for (int j=0;j<4;++j){
    #pragma unroll
    for (int i=0;i<8;++i) acc[j][i]=0.f;
  }

  for (int ch = 0; ch < 4; ++ch) {
    for (int idx = tid; idx < 128*32; idx += 256) {
      int o = idx >> 5, k = idx & 31;
      Ws[k][o] = w2[o*H_ + ch*32 + k];
    }
    __syncthreads();
    #pragma unroll
    for (int k = 0; k < 32; ++k) {
      f32x4 a  = *(const f32x4*)&Hs[ch*32 + k][r0];
      f32x4 wA = *(const f32x4*)&Ws[k][c0];
      f32x4 wB = *(const f32x4*)&Ws[k][c0+4];
      #pragma unroll
      for (int j=0;j<4;++j){
        #pragma unroll
        for (int i=0;i<4;++i){
          acc[j][i]   += a[j]*wA[i];
          acc[j][4+i] += a[j]*wB[i];
        }
      }
    }
    __syncthreads();
  }
  {
    #pragma unroll
    for (int j=0;j<4;++j){
      size_t base = (size_t)(row0 + r0 + j)*H_ + c0;
      #pragma unroll
      for (int i=0;i<8;++i) out[base+i] = eluf(acc[j][i] + b2[c0+i]);
    }
  }
}

// ================= BN apply -> bf16 buffer =================
__global__ __launch_bounds__(128)
void norm_to_bf16(const float* __restrict__ buf, int rows, const float* __restrict__ sums,
                  const float* __restrict__ g, const float* __restrict__ bt,
                  unsigned short* __restrict__ outbf)
{
  int c = threadIdx.x;
  float inv = 1.f/(float)rows;
  float mu  = sums[c]*inv;
  float var = sums[H_+c]*inv - mu*mu;
  float sc  = rsqrtf(var + 1e-5f)*g[c];
  float sh  = bt[c] - mu*sc;
  for (int r = blockIdx.x; r < rows; r += gridDim.x) {
    size_t idx = (size_t)r*H_ + c;
    outbf[idx] = (unsigned short)f2bf_bits(buf[idx]*sc + sh);
  }
}

// ================= MLP2 via MFMA (wave = 32 cols x 64 rows, B in regs) ============
__global__ __launch_bounds__(256, 2)
void mlp2_scatter(const unsigned short* __restrict__ x1bf,
                  const unsigned short* __restrict__ wbf,
                  const float* __restrict__ b21, const float* __restrict__ b22,
                  float* __restrict__ nodeB, float* __restrict__ stats2)
{
  __shared__ int srow[64], rrow[64];
  __shared__ __align__(16) char pool[17408];     // bufH [64*136 ushort]; red aliases
  unsigned short* bufH = (unsigned short*)pool;
  float* red = (float*)pool;                     // [2][128][4]

  const int tid  = threadIdx.x;
  const int bid  = xcd_swizzle(blockIdx.x, gridDim.x);
  const int row0 = bid * 64;
  if (tid < 64) {
    int b,t,sn,ir; edge_decomp(row0 + tid, b, t, sn, ir);
    srow[tid] = (b*N_ + sn)*T_ + t;
    rrow[tid] = (b*N_ + ir)*T_ + t;
  }
  __syncthreads();

  const int lane = tid & 63;
  const int wv   = tid >> 6;          // 0..3
  const int c15  = lane & 15;
  const int k8   = (lane >> 4) * 8;
  const int g4   = (lane >> 4);       // C-row group
  const int colb = wv * 32;
  const unsigned short* W21 = wbf;
  const unsigned short* W22 = wbf + 32768;

  int sA[4], rA[4];
  #pragma unroll
  for (int rt=0;rt<4;++rt){ sA[rt] = srow[rt*16 + c15]; rA[rt] = rrow[rt*16 + c15]; }

  f32x4 C[2][4];

  // ---- P1: [x1 snd | x1 rcv] (K=256) ----
  #pragma unroll
  for (int ci=0;ci<2;++ci){
    float bb = b21[colb + ci*16 + c15];
    #pragma unroll
    for (int rt=0;rt<4;++rt) C[ci][rt] = (f32x4){bb,bb,bb,bb};
  }
  {
    bf16x8 Bf[2][8];
    #pragma unroll
    for (int ci=0;ci<2;++ci){
      #pragma unroll
      for (int kc=0;kc<8;++kc)
        Bf[ci][kc] = *(const bf16x8*)&W21[(size_t)(colb+ci*16+c15)*256 + kc*32 + k8];
    }
    #pragma unroll
    for (int kc=0;kc<8;++kc){
      bf16x8 A[4];
      #pragma unroll
      for (int rt=0;rt<4;++rt){
        int nrow = (kc<4) ? sA[rt] : rA[rt];
        A[rt] = *(const bf16x8*)&x1bf[(size_t)nrow*H_ + (kc&3)*32 + k8];
      }
      #pragma unroll
      for (int ci=0;ci<2;++ci){
        #pragma unroll
        for (int rt=0;rt<4;++rt)
          C[ci][rt] = __builtin_amdgcn_mfma_f32_16x16x32_bf16(A[rt], Bf[ci][kc], C[ci][rt], 0,0,0);
      }
    }
  }
  #pragma unroll
  for (int ci=0;ci<2;++ci){
    #pragma unroll
    for (int rt=0;rt<4;++rt){
      #pragma unroll
      for (int rr=0;rr<4;++rr){
        int row = rt*16 + g4*4 + rr;
        bufH[row*136 + colb + ci*16 + c15] = (unsigned short)f2bf_bits(eluf(C[ci][rt][rr]));
      }
    }
  }
  __syncthreads();

  // ---- P2: H1 (K=128) -> x2 raw ----
  #pragma unroll
  for (int ci=0;ci<2;++ci){
    float bb = b22[colb + ci*16 + c15];
    #pragma unroll
    for (int rt=0;rt<4;++rt) C[ci][rt] = (f32x4){bb,bb,bb,bb};
  }
  {
    bf16x8 Bf[2][4];
    #pragma unroll
    for (int ci=0;ci<2;++ci){
      #pragma unroll
      for (int kc=0;kc<4;++kc)
        Bf[ci][kc] = *(const bf16x8*)&W22[(size_t)(colb+ci*16+c15)*128 + kc*32 + k8];
    }
    #pragma unroll
    for (int kc=0;kc<4;++kc){
      bf16x8 A[4];
      #pragma unroll
      for (int rt=0;rt<4;++rt)
        A[rt] = *(const bf16x8*)&bufH[(rt*16+c15)*136 + kc*32 + k8];
      #pragma unroll
      for (int ci=0;ci<2;++ci){
        #pragma unroll
        for (int rt=0;rt<4;++rt)
          C[ci][rt] = __builtin_amdgcn_mfma_f32_16x16x32_bf16(A[rt], Bf[ci][kc], C[ci][rt], 0,0,0);
      }
    }
  }

  // ---- epilogue: elu, scatter to nodeB, BN2 stats ----
  float s1l[2], s2l[2];
  #pragma unroll
  for (int ci=0;ci<2;++ci){ s1l[ci]=0.f; s2l[ci]=0.f; }
  #pragma unroll
  for (int ci=0;ci<2;++ci){
    int col = colb + ci*16 + c15;
    #pragma unroll
    for (int rt=0;rt<4;++rt){
      #pragma unroll
      for (int rr=0;rr<4;++rr){
        int row = rt*16 + g4*4 + rr;
        float v = eluf(C[ci][rt][rr]);
        atomicAdd(&nodeB[(size_t)rrow[row]*H_ + col], v);
        s1l[ci] += v; s2l[ci] += v*v;
      }
    }
  }
  __syncthreads();            // bufH dead -> reuse as red
  #pragma unroll
  for (int ci=0;ci<2;++ci){
    int col = colb + ci*16 + c15;
    red[col*4 + g4]       = s1l[ci];
    red[512 + col*4 + g4] = s2l[ci];
  }
  __syncthreads();
  if (tid < 128) {
    float s=0.f, q=0.f;
    #pragma unroll
    for (int u=0;u<4;++u){ s += red[tid*4+u]; q += red[512 + tid*4+u]; }
    atomicAdd(&stats2[tid], s);
    atomicAdd(&stats2[128+tid], q);
  }
}

// ================= MLP2-recompute + MLP4 (wave = 32 cols x 64 rows) ==============
__global__ __launch_bounds__(256, 2)
void mlp24_fused(const unsigned short* __restrict__ x1bf, const unsigned short* __restrict__ x3bf,
                 const float* __restrict__ aff2, const unsigned short* __restrict__ wbf,
                 const float* __restrict__ b21, const float* __restrict__ b22,
                 const float* __restrict__ b41, const float* __restrict__ b42,
                 unsigned short* __restrict__ x4pre, float* __restrict__ stats4)
{
  __shared__ int srow[64], rrow[64];
  __shared__ __align__(16) char pool[34816];     // bufH | bufX ; red aliases bufH
  unsigned short* bufH = (unsigned short*)pool;
  unsigned short* bufX = (unsigned short*)(pool + 17408);
  float* red = (float*)pool;

  const int tid  = threadIdx.x;
  const int bid  = xcd_swizzle(blockIdx.x, gridDim.x);
  const int row0 = bid * 64;
  if (tid < 64) {
    int b,t,sn,ir; edge_decomp(row0 + tid, b, t, sn, ir);
    srow[tid] = (b*N_ + sn)*T_ + t;
    rrow[tid] = (b*N_ + ir)*T_ + t;
  }
  __syncthreads();

  const int lane = tid & 63;
  const int wv   = tid >> 6;
  const int c15  = lane & 15;
  const int k8   = (lane >> 4) * 8;
  const int g4   = (lane >> 4);
  const int colb = wv * 32;
  const unsigned short* W21 = wbf;
  const unsigned short* W22 = wbf + 32768;
  const unsigned short* W41 = wbf + 49152;
  const unsigned short* W42 = wbf + 98304;

  int sA[4], rA[4];
  #pragma unroll
  for (int rt=0;rt<4;++rt){ sA[rt] = srow[rt*16 + c15]; rA[rt] = rrow[rt*16 + c15]; }

  f32x4 C[2][4];

  // ---------- P1: MLP2 L1 (K=256) -> bufH ----------
  #pragma unroll
  for (int ci=0;ci<2;++ci){
    float bb = b21[colb + ci*16 + c15];
    #pragma unroll
    for (int rt=0;rt<4;++rt) C[ci][rt] = (f32x4){bb,bb,bb,bb};
  }
  {
    bf16x8 Bf[2][8];
    #pragma unroll
    for (int ci=0;ci<2;++ci){
      #pragma unroll
      for (int kc=0;kc<8;++kc)
        Bf[ci][kc] = *(const bf16x8*)&W21[(size_t)(colb+ci*16+c15)*256 + kc*32 + k8];
    }
    #pragma unroll
    for (int kc=0;kc<8;++kc){
      bf16x8 A[4];
      #pragma unroll
      for (int rt=0;rt<4;++rt){
        int nrow = (kc<4) ? sA[rt] : rA[rt];
        A[rt] = *(const bf16x8*)&x1bf[(size_t)nrow*H_ + (kc&3)*32 + k8];
      }
      #pragma unroll
      for (int ci=0;ci<2;++ci){
        #pragma unroll
        for (int rt=0;rt<4;++rt)
          C[ci][rt] = __builtin_amdgcn_mfma_f32_16x16x32_bf16(A[rt], Bf[ci][kc], C[ci][rt], 0,0,0);
      }
    }
  }
  #pragma unroll
  for (int ci=0;ci<2;++ci){
    #pragma unroll
    for (int rt=0;rt<4;++rt){
      #pragma unroll
      for (int rr=0;rr<4;++rr){
        int row = rt*16 + g4*4 + rr;
        bufH[row*136 + colb + ci*16 + c15] = (unsigned short)f2bf_bits(eluf(C[ci][rt][rr]));
      }
    }
  }
  __syncthreads();

  // ---------- P2: MLP2 L2 (K=128) -> bufX = elu()*aff2 ----------
  #pragma unroll
  for (int ci=0;ci<2;++ci){
    float bb = b22[colb + ci*16 + c15];
    #pragma unroll
    for (int rt=0;rt<4;++rt) C[ci][rt] = (f32x4){bb,bb,bb,bb};
  }
  {
    bf16x8 Bf[2][4];
    #pragma unroll
    for (int ci=0;ci<2;++ci){
      #pragma unroll
      for (int kc=0;kc<4;++kc)
        Bf[ci][kc] = *(const bf16x8*)&W22[(size_t)(colb+ci*16+c15)*128 + kc*32 + k8];
    }
    #pragma unroll
    for (int kc=0;kc<4;++kc){
      bf16x8 A[4];
      #pragma unroll
      for (int rt=0;rt<4;++rt)
        A[rt] = *(const bf16x8*)&bufH[(rt*16+c15)*136 + kc*32 + k8];
      #pragma unroll
      for (int ci=0;ci<2;++ci){
        #pragma unroll
        for (int rt=0;rt<4;++rt)
          C[ci][rt] = __builtin_amdgcn_mfma_f32_16x16x32_bf16(A[rt], Bf[ci][kc], C[ci][rt], 0,0,0);
      }
    }
  }
  #pragma unroll
  for (int ci=0;ci<2;++ci){
    int col = colb + ci*16 + c15;
    float sc = aff2[col], sh = aff2[128+col];
    #pragma unroll
    for (int rt=0;rt<4;++rt){
      #pragma unroll
      for (int rr=0;rr<4;++rr){
        int row = rt*16 + g4*4 + rr;
        bufX[row*136 + col] = (unsigned short)f2bf_bits(eluf(C[ci][rt][rr])*sc + sh);
      }
    }
  }
  __syncthreads();

  // ---------- P3: MLP4 L1 (K=384 = x3snd|x3rcv|X2) -> bufH ----------
  #pragma unroll
  for (int ci=0;ci<2;++ci){
    float bb = b41[colb + ci*16 + c15];
    #pragma unroll
    for (int rt=0;rt<4;++rt) C[ci][rt] = (f32x4){bb,bb,bb,bb};
  }
  {
    bf16x8 Bf[2][6];
    // batch 1: kc = 0..5
    #pragma unroll
    for (int ci=0;ci<2;++ci){
      #pragma unroll
      for (int kc=0;kc<6;++kc)
        Bf[ci][kc] = *(const bf16x8*)&W41[(size_t)(colb+ci*16+c15)*384 + kc*32 + k8];
    }
    #pragma unroll
    for (int kc=0;kc<6;++kc){
      bf16x8 A[4];
      #pragma unroll
      for (int rt=0;rt<4;++rt){
        if (kc < 4) A[rt] = *(const bf16x8*)&x3bf[(size_t)sA[rt]*H_ + kc*32 + k8];
        else        A[rt] = *(const bf16x8*)&x3bf[(size_t)rA[rt]*H_ + (kc-4)*32 + k8];
      }
      #pragma unroll
      for (int ci=0;ci<2;++ci){
        #pragma unroll
        for (int rt=0;rt<4;++rt)
          C[ci][rt] = __builtin_amdgcn_mfma_f32_16x16x32_bf16(A[rt], Bf[ci][kc], C[ci][rt], 0,0,0);
      }
    }
    // batch 2: kc = 6..11
    #pragma unroll
    for (int ci=0;ci<2;++ci){
      #pragma unroll
      for (int kc=0;kc<6;++kc)
        Bf[ci][kc] = *(const bf16x8*)&W41[(size_t)(colb+ci*16+c15)*384 + (kc+6)*32 + k8];
    }
    #pragma unroll
    for (int kc=6;kc<12;++kc){
      bf16x8 A[4];
      #pragma unroll
      for (int rt=0;rt<4;++rt){
        if (kc < 8) A[rt] = *(const bf16x8*)&x3bf[(size_t)rA[rt]*H_ + (kc-4)*32 + k8];
        else        A[rt] = *(const bf16x8*)&bufX[(rt*16+c15)*136 + (kc-8)*32 + k8];
      }
      #pragma unroll
      for (int ci=0;ci<2;++ci){
        #pragma unroll
        for (int rt=0;rt<4;++rt)
          C[ci][rt] = __builtin_amdgcn_mfma_f32_16x16x32_bf16(A[rt], Bf[ci][kc-6], C[ci][rt], 0,0,0);
      }
    }
  }
  __syncthreads();   // all bufX reads + prior bufH reads done before bufH overwrite
  #pragma unroll
  for (int ci=0;ci<2;++ci){
    #pragma unroll
    for (int rt=0;rt<4;++rt){
      #pragma unroll
      for (int rr=0;rr<4;++rr){
        int row = rt*16 + g4*4 + rr;
        bufH[row*136 + colb + ci*16 + c15] = (unsigned short)f2bf_bits(eluf(C[ci][rt][rr]));
      }
    }
  }
  __syncthreads();

  // ---------- P4: MLP4 L2 (K=128) -> x4pre bf16 + stats ----------
  #pragma unroll
  for (int ci=0;ci<2;++ci){
    float bb = b42[colb + ci*16 + c15];
    #pragma unroll
    for (int rt=0;rt<4;++rt) C[ci][rt] = (f32x4){bb,bb,bb,bb};
  }
  {
    bf16x8 Bf[2][4];
    #pragma unroll
    for (int ci=0;ci<2;++ci){
      #pragma unroll
      for (int kc=0;kc<4;++kc)
        Bf[ci][kc] = *(const bf16x8*)&W42[(size_t)(colb+ci*16+c15)*128 + kc*32 + k8];
    }
    #pragma unroll
    for (int kc=0;kc<4;++kc){
      bf16x8 A[4];
      #pragma unroll
      for (int rt=0;rt<4;++rt)
        A[rt] = *(const bf16x8*)&bufH[(rt*16+c15)*136 + kc*32 + k8];
      #pragma unroll
      for (int ci=0;ci<2;++ci){
        #pragma unroll
        for (int rt=0;rt<4;++rt)
          C[ci][rt] = __builtin_amdgcn_mfma_f32_16x16x32_bf16(A[rt], Bf[ci][kc], C[ci][rt], 0,0,0);
      }
    }
  }
  float s1l[2], s2l[2];
  #pragma unroll
  for (int ci=0;ci<2;++ci){ s1l[ci]=0.f; s2l[ci]=0.f; }
  #pragma unroll
  for (int ci=0;ci<2;++ci){
    int col = colb + ci*16 + c15;
    #pragma unroll
    for (int rt=0;rt<4;++rt){
      #pragma unroll
      for (int rr=0;rr<4;++rr){
        int row = rt*16 + g4*4 + rr;
        float v = eluf(C[ci][rt][rr]);
        x4pre[(size_t)(row0 + row)*H_ + col] = (unsigned short)f2bf_bits(v);
        s1l[ci] += v; s2l[ci] += v*v;
      }
    }
  }
  __syncthreads();            // bufH dead -> reuse as red
  #pragma unroll
  for (int ci=0;ci<2;++ci){
    int col = colb + ci*16 + c15;
    red[col*4 + g4]       = s1l[ci];
    red[512 + col*4 + g4] = s2l[ci];
  }
  __syncthreads();
  if (tid < 128) {
    float s=0.f, q=0.f;
    #pragma unroll
    for (int u=0;u<4;++u){ s += red[tid*4+u]; q += red[512 + tid*4+u]; }
    atomicAdd(&stats4[tid], s);
    atomicAdd(&stats4[128+tid], q);
  }
}

// ================= batchnorm helpers =================
__global__ __launch_bounds__(128)
void stats_kernel(const float* __restrict__ buf, int rows, float* __restrict__ sums)
{
  int c = threadIdx.x;
  float s = 0.f, s2 = 0.f;
  for (int r = blockIdx.x; r < rows; r += gridDim.x) {
    float v = buf[(size_t)r*H_ + c];
    s += v; s2 += v*v;
  }
  atomicAdd(&sums[c], s);
  atomicAdd(&sums[H_ + c], s2);
}

__global__ __launch_bounds__(128)
void finalize_aff(const float* __restrict__ sums, const float* __restrict__ g,
                  const float* __restrict__ bt, float* __restrict__ aff, int rows)
{
  int c = threadIdx.x;
  float inv = 1.f/(float)rows;
  float mu  = sums[c]*inv;
  float var = sums[H_+c]*inv - mu*mu;
  float sc  = rsqrtf(var + 1e-5f)*g[c];
  aff[c]      = sc;
  aff[H_ + c] = bt[c] - mu*sc;
}

// nodeB holds raw sums of 29 pre-BN x2 rows; apply aff2 and /N
__global__ __launch_bounds__(256)
void e2n_finalize(float* __restrict__ nodeB, const float* __restrict__ aff2)
{
  int idx = blockIdx.x*256 + threadIdx.x;
  if (idx >= RN*H_) return;
  int c = idx & 127;
  nodeB[idx] = (nodeB[idx]*aff2[c] + (float)(N_-1)*aff2[128+c]) * (1.f/(float)N_);
}

// ===== bidirectional GRU via MFMA: split-gate wave specialization (16 waves) =====
// Wave pair (cg, cg+8), cols [cg*16, cg*16+16):
//   A wave (wv<8):  Cr (K=256) + Ci (K=128, x-side); passes sigmoid(r), Ci via LDS
//   B wave (wv>=8): Cz (K=256) + Cn (K=128, h-side); owns hreg + h update
// 3 barriers/step. h kept bf16 in As; projections read bf16 h.
__global__ __launch_bounds__(1024, 1)
void gru_kernel(const unsigned short* __restrict__ x4raw, const float* __restrict__ aff4,
                const float* __restrict__ wihf, const float* __restrict__ whhf,
                const float* __restrict__ bihf, const float* __restrict__ bhhf,
                const float* __restrict__ wihr, const float* __restrict__ whhr,
                const float* __restrict__ bihr, const float* __restrict__ bhhr,
                const float* __restrict__ pw, const float* __restrict__ pb,
                const float* __restrict__ ew, const float* __restrict__ eb,
                float* __restrict__ out_prior, float* __restrict__ out_enc,
                float* __restrict__ out_hT)
{
  __shared__ __align__(16) unsigned short As[64*264];  // [x(128)|h(128)|pad] bf16
  __shared__ float rbuf[8704];    // [cg][row(stride17)] sigmoid(r)
  __shared__ float cibuf[8704];   // [cg][row(stride17)] Ci (i preact)
  __shared__ float sc4[128], sh4[128];
  __shared__ float pws[256];      // pw 2x128
  __shared__ float ews[512];      // ew 2x256

  const int tid  = threadIdx.x;
  const int dir  = blockIdx.x / NB_GRU;
  const int blk  = blockIdx.x % NB_GRU;
  const int seq0 = blk * 64;
  const int lane = tid & 63;
  const int wv   = __builtin_amdgcn_readfirstlane(tid >> 6);  // 0..15
  const int isA  = (wv < 8);
  const int cg   = wv & 7;
  const int j0   = cg * 16;
  const int c15  = lane & 15;
  const int g4   = lane >> 4;       // 0..3
  const int k8g  = g4 * 8;

  const float* wih = dir ? wihr : wihf;
  const float* whh = dir ? whhr : whhf;
  const float* bih = dir ? bihr : bihf;
  const float* bhh = dir ? bhhr : bhhf;

  // ---- shared init ----
  for (int i = tid; i < 64*264; i += 1024) As[i] = 0;
  if (tid < 128) { sc4[tid] = aff4[tid]; sh4[tid] = aff4[128+tid]; }
  for (int i = tid; i < 256; i += 1024) pws[i] = pw[i];
  for (int i = tid; i < 512; i += 1024) ews[i] = ew[i];
  __syncthreads();

  // ---- weights (BN4 folded into wih-side) ----
  // A: W0 = Wr over [x|h] (8 frags), W1 = Wi_x (4 frags)
  // B: W0 = Wz over [x|h] (8 frags), W1 = Wn_h (4 frags)
  const int roff = isA ? 0 : 128;
  bf16x8 W0[8], W1[4];
  #pragma unroll
  for (int kt=0; kt<8; ++kt){
    if (kt < 4)
      W0[kt] = cvt8s(wih + (size_t)(roff+j0+c15)*H_ + kt*32 + k8g, sc4 + kt*32 + k8g);
    else
      W0[kt] = cvt8(whh + (size_t)(roff+j0+c15)*H_ + (kt-4)*32 + k8g);
  }
  if (isA) {
    #pragma unroll
    for (int kt=0; kt<4; ++kt)
      W1[kt] = cvt8s(wih + (size_t)(256+j0+c15)*H_ + kt*32 + k8g, sc4 + kt*32 + k8g);
  } else {
    #pragma unroll
    for (int kt=0; kt<4; ++kt)
      W1[kt] = cvt8(whh + (size_t)(256+j0+c15)*H_ + kt*32 + k8g);
  }
  // bias folds: absorb Wih·sh
  float bias0, bias1;
  {
    float d0=0.f, d1=0.f;
    for (int k=0; k<H_; ++k){
      float shk = sh4[k];
      d0 += wih[(size_t)(roff+j0+c15)*H_ + k]*shk;
      if (isA) d1 += wih[(size_t)(256+j0+c15)*H_ + k]*shk;
    }
    bias0 = bih[roff+j0+c15] + bhh[roff+j0+c15] + d0;
    bias1 = isA ? (bih[256+j0+c15] + d1) : bhh[256+j0+c15];
  }
  const float pb0 = pb[0], pb1 = pb[1], eb0 = eb[0], eb1 = eb[1];

  float hreg[16];          // live in B waves
  #pragma unroll
  for (int i=0;i<16;++i) hreg[i] = 0.f;

  // staging/projection decomposition: all 1024 threads, 4 dwords each
  const int ss = tid >> 4;          // row 0..63
  const int cc = (tid & 15) * 8;    // col start (8 bf16 = 4 dwords)
  const int qq = seq0 + ss;

  // stage x_0; prefetch x_1
  uint32 xw[4];
  {
    int t0 = dir ? (T_-1) : 0;
    if (qq < NSEQ) {
      const uint32* gp = (const uint32*)(x4raw + ((size_t)qq*T_ + t0)*H_ + cc);
      #pragma unroll
      for (int u=0;u<4;++u) xw[u] = gp[u];
    } else {
      #pragma unroll
      for (int u=0;u<4;++u) xw[u] = 0;
    }
    uint32* xp = (uint32*)(As + ss*264 + cc);
    #pragma unroll
    for (int u=0;u<4;++u) xp[u] = xw[u];
    if (qq < NSEQ) {
      int t1 = dir ? (T_-2) : 1;
      const uint32* gp = (const uint32*)(x4raw + ((size_t)qq*T_ + t1)*H_ + cc);
      #pragma unroll
      for (int u=0;u<4;++u) xw[u] = gp[u];
    }
  }
  __syncthreads();

  for (int step = 0; step < T_; ++step) {
    const int t = dir ? (T_-1-step) : step;

    // ---- PHASE 1: MFMA ----
    f32x4 C0[4], C1[4];
    #pragma unroll
    for (int rt=0;rt<4;++rt){
      C0[rt] = (f32x4){bias0,bias0,bias0,bias0};
      C1[rt] = (f32x4){bias1,bias1,bias1,bias1};
    }
    if (isA) {
      #pragma unroll
      for (int kt=0; kt<8; ++kt){
        bf16x8 a0 = *(const bf16x8*)&As[(size_t)( 0+c15)*264 + kt*32 + k8g];
        bf16x8 a1 = *(const bf16x8*)&As[(size_t)(16+c15)*264 + kt*32 + k8g];
        bf16x8 a2 = *(const bf16x8*)&As[(size_t)(32+c15)*264 + kt*32 + k8g];
        bf16x8 a3 = *(const bf16x8*)&As[(size_t)(48+c15)*264 + kt*32 + k8g];
        C0[0] = __builtin_amdgcn_mfma_f32_16x16x32_bf16(a0, W0[kt], C0[0], 0,0,0);
        C0[1] = __builtin_amdgcn_mfma_f32_16x16x32_bf16(a1, W0[kt], C0[1], 0,0,0);
        C0[2] = __builtin_amdgcn_mfma_f32_16x16x32_bf16(a2, W0[kt], C0[2], 0,0,0);
        C0[3] = __builtin_amdgcn_mfma_f32_16x16x32_bf16(a3, W0[kt], C0[3], 0,0,0);
        if (kt < 4) {
          C1[0] = __builtin_amdgcn_mfma_f32_16x16x32_bf16(a0, W1[kt], C1[0], 0,0,0);
          C1[1] = __builtin_amdgcn_mfma_f32_16x16x32_bf16(a1, W1[kt], C1[1], 0,0,0);
          C1[2] = __builtin_amdgcn_mfma_f32_16x16x32_bf16(a2, W1[kt], C1[2], 0,0,0);
          C1[3] = __builtin_amdgcn_mfma_f32_16x16x32_bf16(a3, W1[kt], C1[3], 0,0,0);
        }
      }
    } else {
      #pragma unroll
      for (int kt=0; kt<8; ++kt){
        bf16x8 a0 = *(const bf16x8*)&As[(size_t)( 0+c15)*264 + kt*32 + k8g];
        bf16x8 a1 = *(const bf16x8*)&As[(size_t)(16+c15)*264 + kt*32 + k8g];
        bf16x8 a2 = *(const bf16x8*)&As[(size_t)(32+c15)*264 + kt*32 + k8g];
        bf16x8 a3 = *(const bf16x8*)&As[(size_t)(48+c15)*264 + kt*32 + k8g];
        C0[0] = __builtin_amdgcn_mfma_f32_16x16x32_bf16(a0, W0[kt], C0[0], 0,0,0);
        C0[1] = __builtin_amdgcn_mfma_f32_16x16x32_bf16(a1, W0[kt], C0[1], 0,0,0);
        C0[2] = __builtin_amdgcn_mfma_f32_16x16x32_bf16(a2, W0[kt], C0[2], 0,0,0);
        C0[3] = __builtin_amdgcn_mfma_f32_16x16x32_bf16(a3, W0[kt], C0[3], 0,0,0);
        if (kt >= 4) {
          C1[0] = __builtin_amdgcn_mfma_f32_16x16x32_bf16(a0, W1[kt-4], C1[0], 0,0,0);
          C1[1] = __builtin_amdgcn_mfma_f32_16x16x32_bf16(a1, W1[kt-4], C1[1], 0,0,0);
          C1[2] = __builtin_amdgcn_mfma_f32_16x16x32_bf16(a2, W1[kt-4], C1[2], 0,0,0);
          C1[3] = __builtin_amdgcn_mfma_f32_16x16x32_bf16(a3, W1[kt-4], C1[3], 0,0,0);
        }
      }
    }
    __syncthreads();   // bar B: all As reads done

    // ---- PHASE 2: commit x_{t+1}; A: sigmoid(r)+Ci -> LDS; B: z=sigmoid; prefetch ----
    if (step + 1 < T_) {
      uint32* xp = (uint32*)(As + ss*264 + cc);
      #pragma unroll
      for (int u=0;u<4;++u) xp[u] = xw[u];
    }
    if (isA) {
      #pragma unroll
      for (int rt=0;rt<4;++rt){
        #pragma unroll
        for (int rr=0;rr<4;++rr){
          int row = rt*16 + g4*4 + rr;
          int slot = cg*1088 + row*17 + c15;
          rbuf[slot]  = sigmoidf(C0[rt][rr]);
          cibuf[slot] = C1[rt][rr];
        }
      }
    } else {
      #pragma unroll
      for (int rt=0;rt<4;++rt){
        #pragma unroll
        for (int rr=0;rr<4;++rr)
          C0[rt][rr] = sigmoidf(C0[rt][rr]);   // z gate
      }
    }
    if (step + 2 < T_ && qq < NSEQ) {
      int tn = dir ? (T_-3-step) : (step+2);
      const uint32* gp = (const uint32*)(x4raw + ((size_t)qq*T_ + tn)*H_ + cc);
      #pragma unroll
      for (int u=0;u<4;++u) xw[u] = gp[u];
    }
    __syncthreads();   // bar C: rbuf/cibuf + x_{t+1} visible

    // ---- PHASE 3: B waves compute n, update h ----
    if (!isA) {
      #pragma unroll
      for (int rt=0;rt<4;++rt){
        #pragma unroll
        for (int rr=0;rr<4;++rr){
          int row = rt*16 + g4*4 + rr;
          int slot = cg*1088 + row*17 + c15;
          float n_ = tanhfast(cibuf[slot] + rbuf[slot]*C1[rt][rr]);
          float z_ = C0[rt][rr];
          float hn = (1.f - z_)*n_ + z_*hreg[rt*4+rr];
          hreg[rt*4+rr] = hn;
          As[(size_t)row*264 + 128 + j0 + c15] = (unsigned short)f2bf_bits(hn);
        }
      }
    }
    __syncthreads();   // bar D: h_t ready (bf16 in As)

    // ---- PHASE 4: projections (16 threads/seq, 8 cols each) ----
    if (qq < NSEQ) {
      float h[8];
      {
        const uint32* hp = (const uint32*)(As + ss*264 + 128 + cc);
        #pragma unroll
        for (int u=0;u<4;++u){
          uint32 w = hp[u];
          h[2*u]   = __uint_as_float(w << 16);
          h[2*u+1] = __uint_as_float(w & 0xFFFF0000u);
        }
      }
      size_t obase = ((size_t)qq*T_ + t)*2;
      if (dir == 0) {
        float p0=0.f, p1=0.f, e0=0.f, e1=0.f;
        #pragma unroll
        for (int i=0;i<8;++i){
          p0 += h[i]*pws[cc+i];
          p1 += h[i]*pws[128+cc+i];
          e0 += h[i]*ews[cc+i];
          e1 += h[i]*ews[256+cc+i];
        }
        #pragma unroll
        for (int m=1;m<16;m<<=1){
          p0 += __shfl_xor(p0,m); p1 += __shfl_xor(p1,m);
          e0 += __shfl_xor(e0,m); e1 += __shfl_xor(e1,m);
        }
        if ((tid & 15) == 0) {
          out_prior[obase]   = p0 + pb0;
          out_prior[obase+1] = p1 + pb1;
          atomicAdd(&out_enc[obase],   e0);
          atomicAdd(&out_enc[obase+1], e1);
        }
      } else {
        float e0=0.f, e1=0.f;
        #pragma unroll
        for (int i=0;i<8;++i){
          e0 += h[i]*ews[128+cc+i];
          e1 += h[i]*ews[256+128+cc+i];
        }
        #pragma unroll
        for (int m=1;m<16;m<<=1){
          e0 += __shfl_xor(e0,m); e1 += __shfl_xor(e1,m);
        }
        if ((tid & 15) == 0) {
          atomicAdd(&out_enc[obase],   e0 + eb0);
          atomicAdd(&out_enc[obase+1], e1 + eb1);
        }
      }
    }
  }

  if (dir == 0) {
    __syncthreads();
    for (int idx = tid; idx < 64*H_; idx += 1024) {
      int s = idx >> 7, c = idx & 127;
      int q = seq0 + s;
      if (q < NSEQ) out_hT[(size_t)q*H_ + c] = bf2f(As[s*264 + 128 + c]);
    }
  }
}

// diagnostic: report ws_size via absmax
__global__ void ws_report(float* out, float v){ out[0] = v; }

// ================= host launcher =================
extern "C" void kernel_launch(void* const* d_in, const int* in_sizes, int n_in,
                              void* d_out, int out_size, void* d_ws, size_t ws_size,
                              hipStream_t stream)
{
  (void)in_sizes; (void)n_in; (void)out_size;
  const float* inputs = (const float*)d_in[0];
  const float* m1_w1 = (const float*)d_in[3];  const float* m1_b1 = (const float*)d_in[4];
  const float* m1_w2 = (const float*)d_in[5];  const float* m1_b2 = (const float*)d_in[6];
  const float* m1_g  = (const float*)d_in[7];  const float* m1_bt = (const float*)d_in[8];
  const float* m2_w1 = (const float*)d_in[9];  const float* m2_b1 = (const float*)d_in[10];
  const float* m2_w2 = (const float*)d_in[11]; const float* m2_b2 = (const float*)d_in[12];
  const float* m2_g  = (const float*)d_in[13]; const float* m2_bt = (const float*)d_in[14];
  const float* m3_w1 = (const float*)d_in[15]; const float* m3_b1 = (const float*)d_in[16];
  const float* m3_w2 = (const float*)d_in[17]; const float* m3_b2 = (const float*)d_in[18];
  const float* m3_g  = (const float*)d_in[19]; const float* m3_bt = (const float*)d_in[20];
  const float* m4_w1 = (const float*)d_in[21]; const float* m4_b1 = (const float*)d_in[22];
  const float* m4_w2 = (const float*)d_in[23]; const float* m4_b2 = (const float*)d_in[24];
  const float* m4_g  = (const float*)d_in[25]; const float* m4_bt = (const float*)d_in[26];
  const float* gf_wih = (const float*)d_in[27]; const float* gf_whh = (const float*)d_in[28];
  const float* gf_bih = (const float*)d_in[29]; const float* gf_bhh = (const float*)d_in[30];
  const float* gr_wih = (const float*)d_in[31]; const float* gr_whh = (const float*)d_in[32];
  const float* gr_bih = (const float*)d_in[33]; const float* gr_bhh = (const float*)d_in[34];
  const float* pw = (const float*)d_in[35]; const float* pb = (const float*)d_in[36];
  const float* ew = (const float*)d_in[37]; const float* eb = (const float*)d_in[38];

  float* out       = (float*)d_out;
  float* out_prior = out;
  float* out_enc   = out + (size_t)RE*2;
  float* out_hT    = out + (size_t)RE*4;

  size_t x4elems = (size_t)RE*H_;
  size_t nodeElems = (size_t)RN*H_;
  unsigned short* x4pre = (unsigned short*)d_ws;
  float* nodeA = (float*)(x4pre + x4elems);           // MLP1 pre-BN
  float* nodeB = nodeA + nodeElems;                   // e2n accumulator
  float* nodeC = nodeB + nodeElems;                   // MLP3 pre-BN
  float* stats = nodeC + nodeElems;                   // 1024 floats
  float* aff   = stats + 1024;                        // aff2, aff4
  unsigned short* wbf  = (unsigned short*)(aff + 512);// 114688 bf16
  unsigned short* x1bf = wbf + 114688;                // RN*H bf16
  unsigned short* x3bf = (unsigned short*)nodeA;      // aliases nodeA (dead after BN1)
  size_t need = (size_t)((char*)(x1bf + nodeElems) - (char*)d_ws);
  if (ws_size < need) {
    ws_report<<<1, 1, 0, stream>>>(out_prior, (float)ws_size);
    return;
  }

  (void)hipMemsetAsync(stats, 0, 1024*sizeof(float), stream);
  (void)hipMemsetAsync(nodeB, 0, nodeElems*sizeof(float), stream);
  (void)hipMemsetAsync(out_enc, 0, (size_t)RE*2*sizeof(float), stream);

  prep_weights<<<448, 256, 0, stream>>>(m2_w1, m2_w2, m4_w1, m4_w2, wbf);

  // MLP1 -> nodeA (pre-BN); BN1 -> x1bf (bf16)
  mlp_fused<0, FIN><<<RN/64, 256, 0, stream>>>(inputs, m1_w1, m1_b1, m1_w2, m1_b2, nodeA);
  stats_kernel<<<512, 128, 0, stream>>>(nodeA, RN, stats + 0);
  norm_to_bf16<<<512, 128, 0, stream>>>(nodeA, RN, stats + 0, m1_g, m1_bt, x1bf);

  // MLP2 (MFMA, no x2 store): BN2 stats + scatter raw x2 into nodeB
  mlp2_scatter<<<RE/64, 256, 0, stream>>>(x1bf, wbf, m2_b1, m2_b2, nodeB, stats + 256);
  finalize_aff<<<1, 128, 0, stream>>>(stats + 256, m2_g, m2_bt, aff + 0, RE);
  e2n_finalize<<<(RN*H_ + 255)/256, 256, 0, stream>>>(nodeB, aff + 0);

  // MLP3 -> nodeC (pre-BN); BN3 -> x3bf (bf16, aliases dead nodeA)
  mlp_fused<2, H_><<<RN/64, 256, 0, stream>>>(nodeB, m3_w1, m3_b1, m3_w2, m3_b2, nodeC);
  stats_kernel<<<512, 128, 0, stream>>>(nodeC, RN, stats + 512);
  norm_to_bf16<<<512, 128, 0, stream>>>(nodeC, RN, stats + 512, m3_g, m3_bt, x3bf);

  // MLP2-recompute + MLP4 (MFMA) -> x4pre bf16 + BN4 stats
  mlp24_fused<<<RE/64, 256, 0, stream>>>(x1bf, x3bf, aff + 0, wbf,
      m2_b1, m2_b2, m4_b1, m4_b2, x4pre, stats + 768);
  finalize_aff<<<1, 128, 0, stream>>>(stats + 768, m4_g, m4_bt, aff + 256, RE);

  // bidirectional GRU (MFMA, split-gate 16-wave) + fused projections
  gru_kernel<<<2*NB_GRU, 1024, 0, stream>>>(x4pre, aff + 256,
      gf_wih, gf_whh, gf_bih, gf_bhh,
      gr_wih, gr_whh, gr_bih, gr_bhh,
      pw, pb, ew, eb, out_prior, out_enc, out_hT);
}

// Round 14
// 1953.869 us; speedup vs baseline: 1.2722x; 1.2722x over previous
//
#include <hip/hip_runtime.h>
#include <math.h>

typedef float f32x4 __attribute__((ext_vector_type(4)));
typedef short bf16x8 __attribute__((ext_vector_type(8)));
typedef unsigned int uint32;
#define DEV static __device__ __forceinline__

constexpr int B_ = 8, N_ = 30, T_ = 100, FIN = 4, H_ = 128;
constexpr int E_ = N_*(N_-1);          // 870
constexpr int NSEQ = B_*E_;            // 6960
constexpr int RN = B_*N_*T_;           // 24000 node rows
constexpr int RE = B_*E_*T_;           // 696000 edge rows
constexpr int ET = E_*T_;              // 87000
constexpr int NB_GRU = (NSEQ + 63)/64; // 109

DEV float eluf(float x){ return x > 0.f ? x : __expf(x) - 1.f; }
DEV float sigmoidf(float x){ return 1.f/(1.f + __expf(-x)); }
DEV float tanhfast(float x){
  float cx = fminf(fmaxf(x, -20.f), 20.f);
  float e = __expf(2.f*cx);
  return (e - 1.f)/(e + 1.f);
}
DEV float dot4(f32x4 a, f32x4 b){ return a[0]*b[0] + a[1]*b[1] + a[2]*b[2] + a[3]*b[3]; }

DEV float bf2f(unsigned short u){ return __uint_as_float(((uint32)u) << 16); }
DEV uint32 f2bf_bits(float f){ uint32 b = __float_as_uint(f); return (b + 0x7FFFu + ((b >> 16) & 1u)) >> 16; }
DEV uint32 pack2(float lo, float hi){ return f2bf_bits(lo) | (f2bf_bits(hi) << 16); }

// load 8 consecutive floats, round to 8 bf16
DEV bf16x8 cvt8(const float* __restrict__ p){
  f32x4 a = *(const f32x4*)p;
  f32x4 b = *(const f32x4*)(p+4);
  bf16x8 r;
  r[0]=(short)f2bf_bits(a[0]); r[1]=(short)f2bf_bits(a[1]);
  r[2]=(short)f2bf_bits(a[2]); r[3]=(short)f2bf_bits(a[3]);
  r[4]=(short)f2bf_bits(b[0]); r[5]=(short)f2bf_bits(b[1]);
  r[6]=(short)f2bf_bits(b[2]); r[7]=(short)f2bf_bits(b[3]);
  return r;
}
// same but element-wise scaled (BN fold)
DEV bf16x8 cvt8s(const float* __restrict__ p, const float* __restrict__ sc){
  bf16x8 r;
  #pragma unroll
  for (int e=0;e<8;++e) r[e] = (short)f2bf_bits(p[e]*sc[e]);
  return r;
}

// decompose edge row -> b, t, sender node, receiver node
DEV void edge_decomp(int row, int& b, int& t, int& sn, int& ir)
{
  b = row / ET;
  int rem = row - b*ET;
  int e   = rem / T_;
  t = rem - e*T_;
  ir = e / (N_-1);
  int j = e - ir*(N_-1);
  sn = j + (j >= ir ? 1 : 0);
}

// bijective XCD swizzle (m204)
DEV int xcd_swizzle(int orig, int nwg)
{
  int q = nwg >> 3, r = nwg & 7;
  int xcd = orig & 7, j = orig >> 3;
  return (xcd < r ? xcd*(q+1) : r*(q+1) + (xcd-r)*q) + j;
}

// ================= weight prep: fp32 -> bf16 (w21|w22|w41|w42) =================
__global__ __launch_bounds__(256)
void prep_weights(const float* __restrict__ w21, const float* __restrict__ w22,
                  const float* __restrict__ w41, const float* __restrict__ w42,
                  unsigned short* __restrict__ wbf)
{
  int idx = blockIdx.x*256 + threadIdx.x;
  if (idx >= 114688) return;
  float v;
  if (idx < 32768)      v = w21[idx];
  else if (idx < 49152) v = w22[idx - 32768];
  else if (idx < 98304) v = w41[idx - 49152];
  else                  v = w42[idx - 98304];
  wbf[idx] = (unsigned short)f2bf_bits(v);
}

// ================= simple fused 2-layer MLP (node-sized, fp32 out) =================
template<int MODE, int DIN>
__global__ __launch_bounds__(256)
void mlp_fused(const float* __restrict__ src,
               const float* __restrict__ w1, const float* __restrict__ b1,
               const float* __restrict__ w2, const float* __restrict__ b2,
               float* __restrict__ out)
{
  constexpr int KC  = (DIN < 32) ? DIN : 32;
  constexpr int NCH = DIN / KC;
  __shared__ float As[KC][68];
  __shared__ float Ws[32][132];
  __shared__ float Hs[128][68];

  const int tid  = threadIdx.x;
  const int row0 = blockIdx.x * 64;
  const int tx = tid & 15, ty = tid >> 4;
  const int c0 = tx*8, r0 = ty*4;

  float acc[4][8];
  #pragma unroll
  for (int j=0;j<4;++j){
    #pragma unroll
    for (int i=0;i<8;++i) acc[j][i]=0.f;
  }

  for (int ch = 0; ch < NCH; ++ch) {
    for (int idx = tid; idx < 64*KC; idx += 256) {
      int r = idx / KC, k = idx % KC;
      As[k][r] = src[(size_t)(row0 + r)*DIN + ch*KC + k];
    }
    for (int idx = tid; idx < 128*KC; idx += 256) {
      int o = idx / KC, k = idx % KC;
      Ws[k][o] = w1[o*DIN + ch*KC + k];
    }
    __syncthreads();
    #pragma unroll
    for (int k = 0; k < KC; ++k) {
      f32x4 a  = *(const f32x4*)&As[k][r0];
      f32x4 wA = *(const f32x4*)&Ws[k][c0];
      f32x4 wB = *(const f32x4*)&Ws[k][c0+4];
      #pragma unroll
      for (int j=0;j<4;++j){
        #pragma unroll
        for (int i=0;i<4;++i){
          acc[j][i]   += a[j]*wA[i];
          acc[j][4+i] += a[j]*wB[i];
        }
      }
    }
    __syncthreads();
  }
  {
    #pragma unroll
    for (int i=0;i<8;++i){
      float bb = b1[c0+i];
      #pragma unroll
      for (int j=0;j<4;++j)
        Hs[c0+i][r0+j] = eluf(acc[j][i] + bb);
    }
  }
  __syncthreads();

  #pragma unroll
  for (int j=0;j<4;++j){
    #pragma unroll
    for (int i=0;i<8;++i) acc[j][i]=0.f;
  }

  for (int ch = 0; ch < 4; ++ch) {
    for (int idx = tid; idx < 128*32; idx += 256) {
      int o = idx >> 5, k = idx & 31;
      Ws[k][o] = w2[o*H_ + ch*32 + k];
    }
    __syncthreads();
    #pragma unroll
    for (int k = 0; k < 32; ++k) {
      f32x4 a  = *(const f32x4*)&Hs[ch*32 + k][r0];
      f32x4 wA = *(const f32x4*)&Ws[k][c0];
      f32x4 wB = *(const f32x4*)&Ws[k][c0+4];
      #pragma unroll
      for (int j=0;j<4;++j){
        #pragma unroll
        for (int i=0;i<4;++i){
          acc[j][i]   += a[j]*wA[i];
          acc[j][4+i] += a[j]*wB[i];
        }
      }
    }
    __syncthreads();
  }
  {
    #pragma unroll
    for (int j=0;j<4;++j){
      size_t base = (size_t)(row0 + r0 + j)*H_ + c0;
      #pragma unroll
      for (int i=0;i<8;++i) out[base+i] = eluf(acc[j][i] + b2[c0+i]);
    }
  }
}

// ================= BN apply -> bf16 buffer =================
__global__ __launch_bounds__(128)
void norm_to_bf16(const float* __restrict__ buf, int rows, const float* __restrict__ sums,
                  const float* __restrict__ g, const float* __restrict__ bt,
                  unsigned short* __restrict__ outbf)
{
  int c = threadIdx.x;
  float inv = 1.f/(float)rows;
  float mu  = sums[c]*inv;
  float var = sums[H_+c]*inv - mu*mu;
  float sc  = rsqrtf(var + 1e-5f)*g[c];
  float sh  = bt[c] - mu*sc;
  for (int r = blockIdx.x; r < rows; r += gridDim.x) {
    size_t idx = (size_t)r*H_ + c;
    outbf[idx] = (unsigned short)f2bf_bits(buf[idx]*sc + sh);
  }
}

// ================= MLP2 via MFMA (wave = 32 cols x 64 rows, B in regs) ============
__global__ __launch_bounds__(256, 2)
void mlp2_scatter(const unsigned short* __restrict__ x1bf,
                  const unsigned short* __restrict__ wbf,
                  const float* __restrict__ b21, const float* __restrict__ b22,
                  float* __restrict__ nodeB, float* __restrict__ stats2)
{
  __shared__ int srow[64], rrow[64];
  __shared__ __align__(16) char pool[17408];     // bufH [64*136 ushort]; red aliases
  unsigned short* bufH = (unsigned short*)pool;
  float* red = (float*)pool;                     // [2][128][4]

  const int tid  = threadIdx.x;
  const int bid  = xcd_swizzle(blockIdx.x, gridDim.x);
  const int row0 = bid * 64;
  if (tid < 64) {
    int b,t,sn,ir; edge_decomp(row0 + tid, b, t, sn, ir);
    srow[tid] = (b*N_ + sn)*T_ + t;
    rrow[tid] = (b*N_ + ir)*T_ + t;
  }
  __syncthreads();

  const int lane = tid & 63;
  const int wv   = tid >> 6;          // 0..3
  const int c15  = lane & 15;
  const int k8   = (lane >> 4) * 8;
  const int g4   = (lane >> 4);       // C-row group
  const int colb = wv * 32;
  const unsigned short* W21 = wbf;
  const unsigned short* W22 = wbf + 32768;

  int sA[4], rA[4];
  #pragma unroll
  for (int rt=0;rt<4;++rt){ sA[rt] = srow[rt*16 + c15]; rA[rt] = rrow[rt*16 + c15]; }

  f32x4 C[2][4];

  // ---- P1: [x1 snd | x1 rcv] (K=256) ----
  #pragma unroll
  for (int ci=0;ci<2;++ci){
    float bb = b21[colb + ci*16 + c15];
    #pragma unroll
    for (int rt=0;rt<4;++rt) C[ci][rt] = (f32x4){bb,bb,bb,bb};
  }
  {
    bf16x8 Bf[2][8];
    #pragma unroll
    for (int ci=0;ci<2;++ci){
      #pragma unroll
      for (int kc=0;kc<8;++kc)
        Bf[ci][kc] = *(const bf16x8*)&W21[(size_t)(colb+ci*16+c15)*256 + kc*32 + k8];
    }
    #pragma unroll
    for (int kc=0;kc<8;++kc){
      bf16x8 A[4];
      #pragma unroll
      for (int rt=0;rt<4;++rt){
        int nrow = (kc<4) ? sA[rt] : rA[rt];
        A[rt] = *(const bf16x8*)&x1bf[(size_t)nrow*H_ + (kc&3)*32 + k8];
      }
      #pragma unroll
      for (int ci=0;ci<2;++ci){
        #pragma unroll
        for (int rt=0;rt<4;++rt)
          C[ci][rt] = __builtin_amdgcn_mfma_f32_16x16x32_bf16(A[rt], Bf[ci][kc], C[ci][rt], 0,0,0);
      }
    }
  }
  #pragma unroll
  for (int ci=0;ci<2;++ci){
    #pragma unroll
    for (int rt=0;rt<4;++rt){
      #pragma unroll
      for (int rr=0;rr<4;++rr){
        int row = rt*16 + g4*4 + rr;
        bufH[row*136 + colb + ci*16 + c15] = (unsigned short)f2bf_bits(eluf(C[ci][rt][rr]));
      }
    }
  }
  __syncthreads();

  // ---- P2: H1 (K=128) -> x2 raw ----
  #pragma unroll
  for (int ci=0;ci<2;++ci){
    float bb = b22[colb + ci*16 + c15];
    #pragma unroll
    for (int rt=0;rt<4;++rt) C[ci][rt] = (f32x4){bb,bb,bb,bb};
  }
  {
    bf16x8 Bf[2][4];
    #pragma unroll
    for (int ci=0;ci<2;++ci){
      #pragma unroll
      for (int kc=0;kc<4;++kc)
        Bf[ci][kc] = *(const bf16x8*)&W22[(size_t)(colb+ci*16+c15)*128 + kc*32 + k8];
    }
    #pragma unroll
    for (int kc=0;kc<4;++kc){
      bf16x8 A[4];
      #pragma unroll
      for (int rt=0;rt<4;++rt)
        A[rt] = *(const bf16x8*)&bufH[(rt*16+c15)*136 + kc*32 + k8];
      #pragma unroll
      for (int ci=0;ci<2;++ci){
        #pragma unroll
        for (int rt=0;rt<4;++rt)
          C[ci][rt] = __builtin_amdgcn_mfma_f32_16x16x32_bf16(A[rt], Bf[ci][kc], C[ci][rt], 0,0,0);
      }
    }
  }

  // ---- epilogue: elu, scatter to nodeB, BN2 stats ----
  float s1l[2], s2l[2];
  #pragma unroll
  for (int ci=0;ci<2;++ci){ s1l[ci]=0.f; s2l[ci]=0.f; }
  #pragma unroll
  for (int ci=0;ci<2;++ci){
    int col = colb + ci*16 + c15;
    #pragma unroll
    for (int rt=0;rt<4;++rt){
      #pragma unroll
      for (int rr=0;rr<4;++rr){
        int row = rt*16 + g4*4 + rr;
        float v = eluf(C[ci][rt][rr]);
        atomicAdd(&nodeB[(size_t)rrow[row]*H_ + col], v);
        s1l[ci] += v; s2l[ci] += v*v;
      }
    }
  }
  __syncthreads();            // bufH dead -> reuse as red
  #pragma unroll
  for (int ci=0;ci<2;++ci){
    int col = colb + ci*16 + c15;
    red[col*4 + g4]       = s1l[ci];
    red[512 + col*4 + g4] = s2l[ci];
  }
  __syncthreads();
  if (tid < 128) {
    float s=0.f, q=0.f;
    #pragma unroll
    for (int u=0;u<4;++u){ s += red[tid*4+u]; q += red[512 + tid*4+u]; }
    atomicAdd(&stats2[tid], s);
    atomicAdd(&stats2[128+tid], q);
  }
}

// ================= MLP2-recompute + MLP4 (wave = 32 cols x 64 rows) ==============
__global__ __launch_bounds__(256, 2)
void mlp24_fused(const unsigned short* __restrict__ x1bf, const unsigned short* __restrict__ x3bf,
                 const float* __restrict__ aff2, const unsigned short* __restrict__ wbf,
                 const float* __restrict__ b21, const float* __restrict__ b22,
                 const float* __restrict__ b41, const float* __restrict__ b42,
                 unsigned short* __restrict__ x4pre, float* __restrict__ stats4)
{
  __shared__ int srow[64], rrow[64];
  __shared__ __align__(16) char pool[34816];     // bufH | bufX ; red aliases bufH
  unsigned short* bufH = (unsigned short*)pool;
  unsigned short* bufX = (unsigned short*)(pool + 17408);
  float* red = (float*)pool;

  const int tid  = threadIdx.x;
  const int bid  = xcd_swizzle(blockIdx.x, gridDim.x);
  const int row0 = bid * 64;
  if (tid < 64) {
    int b,t,sn,ir; edge_decomp(row0 + tid, b, t, sn, ir);
    srow[tid] = (b*N_ + sn)*T_ + t;
    rrow[tid] = (b*N_ + ir)*T_ + t;
  }
  __syncthreads();

  const int lane = tid & 63;
  const int wv   = tid >> 6;
  const int c15  = lane & 15;
  const int k8   = (lane >> 4) * 8;
  const int g4   = (lane >> 4);
  const int colb = wv * 32;
  const unsigned short* W21 = wbf;
  const unsigned short* W22 = wbf + 32768;
  const unsigned short* W41 = wbf + 49152;
  const unsigned short* W42 = wbf + 98304;

  int sA[4], rA[4];
  #pragma unroll
  for (int rt=0;rt<4;++rt){ sA[rt] = srow[rt*16 + c15]; rA[rt] = rrow[rt*16 + c15]; }

  f32x4 C[2][4];

  // ---------- P1: MLP2 L1 (K=256) -> bufH ----------
  #pragma unroll
  for (int ci=0;ci<2;++ci){
    float bb = b21[colb + ci*16 + c15];
    #pragma unroll
    for (int rt=0;rt<4;++rt) C[ci][rt] = (f32x4){bb,bb,bb,bb};
  }
  {
    bf16x8 Bf[2][8];
    #pragma unroll
    for (int ci=0;ci<2;++ci){
      #pragma unroll
      for (int kc=0;kc<8;++kc)
        Bf[ci][kc] = *(const bf16x8*)&W21[(size_t)(colb+ci*16+c15)*256 + kc*32 + k8];
    }
    #pragma unroll
    for (int kc=0;kc<8;++kc){
      bf16x8 A[4];
      #pragma unroll
      for (int rt=0;rt<4;++rt){
        int nrow = (kc<4) ? sA[rt] : rA[rt];
        A[rt] = *(const bf16x8*)&x1bf[(size_t)nrow*H_ + (kc&3)*32 + k8];
      }
      #pragma unroll
      for (int ci=0;ci<2;++ci){
        #pragma unroll
        for (int rt=0;rt<4;++rt)
          C[ci][rt] = __builtin_amdgcn_mfma_f32_16x16x32_bf16(A[rt], Bf[ci][kc], C[ci][rt], 0,0,0);
      }
    }
  }
  #pragma unroll
  for (int ci=0;ci<2;++ci){
    #pragma unroll
    for (int rt=0;rt<4;++rt){
      #pragma unroll
      for (int rr=0;rr<4;++rr){
        int row = rt*16 + g4*4 + rr;
        bufH[row*136 + colb + ci*16 + c15] = (unsigned short)f2bf_bits(eluf(C[ci][rt][rr]));
      }
    }
  }
  __syncthreads();

  // ---------- P2: MLP2 L2 (K=128) -> bufX = elu()*aff2 ----------
  #pragma unroll
  for (int ci=0;ci<2;++ci){
    float bb = b22[colb + ci*16 + c15];
    #pragma unroll
    for (int rt=0;rt<4;++rt) C[ci][rt] = (f32x4){bb,bb,bb,bb};
  }
  {
    bf16x8 Bf[2][4];
    #pragma unroll
    for (int ci=0;ci<2;++ci){
      #pragma unroll
      for (int kc=0;kc<4;++kc)
        Bf[ci][kc] = *(const bf16x8*)&W22[(size_t)(colb+ci*16+c15)*128 + kc*32 + k8];
    }
    #pragma unroll
    for (int kc=0;kc<4;++kc){
      bf16x8 A[4];
      #pragma unroll
      for (int rt=0;rt<4;++rt)
        A[rt] = *(const bf16x8*)&bufH[(rt*16+c15)*136 + kc*32 + k8];
      #pragma unroll
      for (int ci=0;ci<2;++ci){
        #pragma unroll
        for (int rt=0;rt<4;++rt)
          C[ci][rt] = __builtin_amdgcn_mfma_f32_16x16x32_bf16(A[rt], Bf[ci][kc], C[ci][rt], 0,0,0);
      }
    }
  }
  #pragma unroll
  for (int ci=0;ci<2;++ci){
    int col = colb + ci*16 + c15;
    float sc = aff2[col], sh = aff2[128+col];
    #pragma unroll
    for (int rt=0;rt<4;++rt){
      #pragma unroll
      for (int rr=0;rr<4;++rr){
        int row = rt*16 + g4*4 + rr;
        bufX[row*136 + col] = (unsigned short)f2bf_bits(eluf(C[ci][rt][rr])*sc + sh);
      }
    }
  }
  __syncthreads();

  // ---------- P3: MLP4 L1 (K=384 = x3snd|x3rcv|X2) -> bufH ----------
  #pragma unroll
  for (int ci=0;ci<2;++ci){
    float bb = b41[colb + ci*16 + c15];
    #pragma unroll
    for (int rt=0;rt<4;++rt) C[ci][rt] = (f32x4){bb,bb,bb,bb};
  }
  {
    bf16x8 Bf[2][6];
    // batch 1: kc = 0..5
    #pragma unroll
    for (int ci=0;ci<2;++ci){
      #pragma unroll
      for (int kc=0;kc<6;++kc)
        Bf[ci][kc] = *(const bf16x8*)&W41[(size_t)(colb+ci*16+c15)*384 + kc*32 + k8];
    }
    #pragma unroll
    for (int kc=0;kc<6;++kc){
      bf16x8 A[4];
      #pragma unroll
      for (int rt=0;rt<4;++rt){
        if (kc < 4) A[rt] = *(const bf16x8*)&x3bf[(size_t)sA[rt]*H_ + kc*32 + k8];
        else        A[rt] = *(const bf16x8*)&x3bf[(size_t)rA[rt]*H_ + (kc-4)*32 + k8];
      }
      #pragma unroll
      for (int ci=0;ci<2;++ci){
        #pragma unroll
        for (int rt=0;rt<4;++rt)
          C[ci][rt] = __builtin_amdgcn_mfma_f32_16x16x32_bf16(A[rt], Bf[ci][kc], C[ci][rt], 0,0,0);
      }
    }
    // batch 2: kc = 6..11
    #pragma unroll
    for (int ci=0;ci<2;++ci){
      #pragma unroll
      for (int kc=0;kc<6;++kc)
        Bf[ci][kc] = *(const bf16x8*)&W41[(size_t)(colb+ci*16+c15)*384 + (kc+6)*32 + k8];
    }
    #pragma unroll
    for (int kc=6;kc<12;++kc){
      bf16x8 A[4];
      #pragma unroll
      for (int rt=0;rt<4;++rt){
        if (kc < 8) A[rt] = *(const bf16x8*)&x3bf[(size_t)rA[rt]*H_ + (kc-4)*32 + k8];
        else        A[rt] = *(const bf16x8*)&bufX[(rt*16+c15)*136 + (kc-8)*32 + k8];
      }
      #pragma unroll
      for (int ci=0;ci<2;++ci){
        #pragma unroll
        for (int rt=0;rt<4;++rt)
          C[ci][rt] = __builtin_amdgcn_mfma_f32_16x16x32_bf16(A[rt], Bf[ci][kc-6], C[ci][rt], 0,0,0);
      }
    }
  }
  __syncthreads();   // all bufX reads + prior bufH reads done before bufH overwrite
  #pragma unroll
  for (int ci=0;ci<2;++ci){
    #pragma unroll
    for (int rt=0;rt<4;++rt){
      #pragma unroll
      for (int rr=0;rr<4;++rr){
        int row = rt*16 + g4*4 + rr;
        bufH[row*136 + colb + ci*16 + c15] = (unsigned short)f2bf_bits(eluf(C[ci][rt][rr]));
      }
    }
  }
  __syncthreads();

  // ---------- P4: MLP4 L2 (K=128) -> x4pre bf16 + stats ----------
  #pragma unroll
  for (int ci=0;ci<2;++ci){
    float bb = b42[colb + ci*16 + c15];
    #pragma unroll
    for (int rt=0;rt<4;++rt) C[ci][rt] = (f32x4){bb,bb,bb,bb};
  }
  {
    bf16x8 Bf[2][4];
    #pragma unroll
    for (int ci=0;ci<2;++ci){
      #pragma unroll
      for (int kc=0;kc<4;++kc)
        Bf[ci][kc] = *(const bf16x8*)&W42[(size_t)(colb+ci*16+c15)*128 + kc*32 + k8];
    }
    #pragma unroll
    for (int kc=0;kc<4;++kc){
      bf16x8 A[4];
      #pragma unroll
      for (int rt=0;rt<4;++rt)
        A[rt] = *(const bf16x8*)&bufH[(rt*16+c15)*136 + kc*32 + k8];
      #pragma unroll
      for (int ci=0;ci<2;++ci){
        #pragma unroll
        for (int rt=0;rt<4;++rt)
          C[ci][rt] = __builtin_amdgcn_mfma_f32_16x16x32_bf16(A[rt], Bf[ci][kc], C[ci][rt], 0,0,0);
      }
    }
  }
  float s1l[2], s2l[2];
  #pragma unroll
  for (int ci=0;ci<2;++ci){ s1l[ci]=0.f; s2l[ci]=0.f; }
  #pragma unroll
  for (int ci=0;ci<2;++ci){
    int col = colb + ci*16 + c15;
    #pragma unroll
    for (int rt=0;rt<4;++rt){
      #pragma unroll
      for (int rr=0;rr<4;++rr){
        int row = rt*16 + g4*4 + rr;
        float v = eluf(C[ci][rt][rr]);
        x4pre[(size_t)(row0 + row)*H_ + col] = (unsigned short)f2bf_bits(v);
        s1l[ci] += v; s2l[ci] += v*v;
      }
    }
  }
  __syncthreads();            // bufH dead -> reuse as red
  #pragma unroll
  for (int ci=0;ci<2;++ci){
    int col = colb + ci*16 + c15;
    red[col*4 + g4]       = s1l[ci];
    red[512 + col*4 + g4] = s2l[ci];
  }
  __syncthreads();
  if (tid < 128) {
    float s=0.f, q=0.f;
    #pragma unroll
    for (int u=0;u<4;++u){ s += red[tid*4+u]; q += red[512 + tid*4+u]; }
    atomicAdd(&stats4[tid], s);
    atomicAdd(&stats4[128+tid], q);
  }
}

// ================= batchnorm helpers =================
__global__ __launch_bounds__(128)
void stats_kernel(const float* __restrict__ buf, int rows, float* __restrict__ sums)
{
  int c = threadIdx.x;
  float s = 0.f, s2 = 0.f;
  for (int r = blockIdx.x; r < rows; r += gridDim.x) {
    float v = buf[(size_t)r*H_ + c];
    s += v; s2 += v*v;
  }
  atomicAdd(&sums[c], s);
  atomicAdd(&sums[H_ + c], s2);
}

__global__ __launch_bounds__(128)
void finalize_aff(const float* __restrict__ sums, const float* __restrict__ g,
                  const float* __restrict__ bt, float* __restrict__ aff, int rows)
{
  int c = threadIdx.x;
  float inv = 1.f/(float)rows;
  float mu  = sums[c]*inv;
  float var = sums[H_+c]*inv - mu*mu;
  float sc  = rsqrtf(var + 1e-5f)*g[c];
  aff[c]      = sc;
  aff[H_ + c] = bt[c] - mu*sc;
}

// nodeB holds raw sums of 29 pre-BN x2 rows; apply aff2 and /N
__global__ __launch_bounds__(256)
void e2n_finalize(float* __restrict__ nodeB, const float* __restrict__ aff2)
{
  int idx = blockIdx.x*256 + threadIdx.x;
  if (idx >= RN*H_) return;
  int c = idx & 127;
  nodeB[idx] = (nodeB[idx]*aff2[c] + (float)(N_-1)*aff2[128+c]) * (1.f/(float)N_);
}

// ===== bidirectional GRU via MFMA: 64 seqs/block, BN4 folded into weights =====
// 2 barriers/step: [MFMA] barB [gates+h-write+x-commit+prefetch] barC [projections]
__global__ __launch_bounds__(512, 1)
void gru_kernel(const unsigned short* __restrict__ x4raw, const float* __restrict__ aff4,
                const float* __restrict__ wihf, const float* __restrict__ whhf,
                const float* __restrict__ bihf, const float* __restrict__ bhhf,
                const float* __restrict__ wihr, const float* __restrict__ whhr,
                const float* __restrict__ bihr, const float* __restrict__ bhhr,
                const float* __restrict__ pw, const float* __restrict__ pb,
                const float* __restrict__ ew, const float* __restrict__ eb,
                float* __restrict__ out_prior, float* __restrict__ out_enc,
                float* __restrict__ out_hT)
{
  __shared__ __align__(16) unsigned short As[64*264];
  __shared__ __align__(16) float hs[64*132];
  __shared__ float sc4[128], sh4[128];
  __shared__ float pws[256];     // pw 2x128
  __shared__ float ews[512];     // ew 2x256

  const int tid  = threadIdx.x;
  const int dir  = blockIdx.x / NB_GRU;
  const int blk  = blockIdx.x % NB_GRU;
  const int seq0 = blk * 64;
  const int lane = tid & 63;
  const int wv   = __builtin_amdgcn_readfirstlane(tid >> 6);
  const int j0   = wv * 16;
  const int c15  = lane & 15;
  const int k8g  = (lane >> 4) * 8;

  const float* wih = dir ? wihr : wihf;
  const float* whh = dir ? whhr : whhf;
  const float* bih = dir ? bihr : bihf;
  const float* bhh = dir ? bhhr : bhhf;

  // phase 0: shared init (sc4/sh4 needed before weight scaling)
  for (int i = tid; i < 64*264; i += 512) As[i] = 0;
  for (int i = tid; i < 64*132; i += 512) hs[i] = 0.f;
  if (tid < 128) { sc4[tid] = aff4[tid]; sh4[tid] = aff4[128+tid]; }
  for (int i = tid; i < 256; i += 512) pws[i] = pw[i];
  for (int i = tid; i < 512; i += 512) ews[i] = ew[i];
  __syncthreads();

  // weights: wih-part scaled by sc4 (BN fold); whh-part raw
  bf16x8 Br[8], Bz[8], Bi[4], Bn[4];
  #pragma unroll
  for (int kt=0; kt<8; ++kt){
    if (kt < 4) {
      Br[kt] = cvt8s(wih + (size_t)(j0+c15)*H_ + kt*32 + k8g,     sc4 + kt*32 + k8g);
      Bz[kt] = cvt8s(wih + (size_t)(128+j0+c15)*H_ + kt*32 + k8g, sc4 + kt*32 + k8g);
    } else {
      Br[kt] = cvt8(whh + (size_t)(j0+c15)*H_ + (kt-4)*32 + k8g);
      Bz[kt] = cvt8(whh + (size_t)(128+j0+c15)*H_ + (kt-4)*32 + k8g);
    }
  }
  #pragma unroll
  for (int kt=0; kt<4; ++kt){
    Bi[kt] = cvt8s(wih + (size_t)(256+j0+c15)*H_ + kt*32 + k8g, sc4 + kt*32 + k8g);
    Bn[kt] = cvt8(whh + (size_t)(256+j0+c15)*H_ + kt*32 + k8g);
  }
  // biases absorb Wih·sh (BN shift fold)
  float dR=0.f, dZ=0.f, dI=0.f;
  for (int k=0; k<H_; ++k){
    float shk = sh4[k];
    dR += wih[(size_t)(j0+c15)*H_ + k]*shk;
    dZ += wih[(size_t)(128+j0+c15)*H_ + k]*shk;
    dI += wih[(size_t)(256+j0+c15)*H_ + k]*shk;
  }
  const float bR = bih[j0+c15]     + bhh[j0+c15]     + dR;
  const float bZ = bih[128+j0+c15] + bhh[128+j0+c15] + dZ;
  const float bI = bih[256+j0+c15] + dI;
  const float bN = bhh[256+j0+c15];
  const float pb0 = pb[0], pb1 = pb[1], eb0 = eb[0], eb1 = eb[1];

  float hreg[16];
  #pragma unroll
  for (int i=0;i<16;++i) hreg[i] = 0.f;

  const int ss = tid >> 3;          // staging row 0..63
  const int cc = (tid & 7) * 16;    // staging col start (16 bf16 = 8 dwords)
  const int qq = seq0 + ss;

  // stage x_0 directly; prefetch x_1
  uint32 xw[8];
  {
    int t0 = dir ? (T_-1) : 0;
    if (qq < NSEQ) {
      const uint32* gp = (const uint32*)(x4raw + ((size_t)qq*T_ + t0)*H_ + cc);
      #pragma unroll
      for (int u=0;u<8;++u) xw[u] = gp[u];
    } else {
      #pragma unroll
      for (int u=0;u<8;++u) xw[u] = 0;
    }
    uint32* xp = (uint32*)(As + ss*264 + cc);
    #pragma unroll
    for (int u=0;u<8;++u) xp[u] = xw[u];
    if (qq < NSEQ) {
      int t1 = dir ? (T_-2) : 1;
      const uint32* gp = (const uint32*)(x4raw + ((size_t)qq*T_ + t1)*H_ + cc);
      #pragma unroll
      for (int u=0;u<8;++u) xw[u] = gp[u];
    }
  }
  __syncthreads();   // x_0 staged, weights ready

  for (int step = 0; step < T_; ++step) {
    const int t = dir ? (T_-1-step) : step;

    f32x4 Cr[4], Cz[4], Ci[4], Cn[4];
    #pragma unroll
    for (int rt=0;rt<4;++rt){
      Cr[rt] = (f32x4){bR,bR,bR,bR};
      Cz[rt] = (f32x4){bZ,bZ,bZ,bZ};
      Ci[rt] = (f32x4){bI,bI,bI,bI};
      Cn[rt] = (f32x4){bN,bN,bN,bN};
    }
    #pragma unroll
    for (int kt=0; kt<8; ++kt){
      bf16x8 a0 = *(const bf16x8*)&As[(size_t)( 0+c15)*264 + kt*32 + k8g];
      bf16x8 a1 = *(const bf16x8*)&As[(size_t)(16+c15)*264 + kt*32 + k8g];
      bf16x8 a2 = *(const bf16x8*)&As[(size_t)(32+c15)*264 + kt*32 + k8g];
      bf16x8 a3 = *(const bf16x8*)&As[(size_t)(48+c15)*264 + kt*32 + k8g];
      Cr[0] = __builtin_amdgcn_mfma_f32_16x16x32_bf16(a0, Br[kt], Cr[0], 0,0,0);
      Cr[1] = __builtin_amdgcn_mfma_f32_16x16x32_bf16(a1, Br[kt], Cr[1], 0,0,0);
      Cr[2] = __builtin_amdgcn_mfma_f32_16x16x32_bf16(a2, Br[kt], Cr[2], 0,0,0);
      Cr[3] = __builtin_amdgcn_mfma_f32_16x16x32_bf16(a3, Br[kt], Cr[3], 0,0,0);
      Cz[0] = __builtin_amdgcn_mfma_f32_16x16x32_bf16(a0, Bz[kt], Cz[0], 0,0,0);
      Cz[1] = __builtin_amdgcn_mfma_f32_16x16x32_bf16(a1, Bz[kt], Cz[1], 0,0,0);
      Cz[2] = __builtin_amdgcn_mfma_f32_16x16x32_bf16(a2, Bz[kt], Cz[2], 0,0,0);
      Cz[3] = __builtin_amdgcn_mfma_f32_16x16x32_bf16(a3, Bz[kt], Cz[3], 0,0,0);
      if (kt < 4) {
        Ci[0] = __builtin_amdgcn_mfma_f32_16x16x32_bf16(a0, Bi[kt], Ci[0], 0,0,0);
        Ci[1] = __builtin_amdgcn_mfma_f32_16x16x32_bf16(a1, Bi[kt], Ci[1], 0,0,0);
        Ci[2] = __builtin_amdgcn_mfma_f32_16x16x32_bf16(a2, Bi[kt], Ci[2], 0,0,0);
        Ci[3] = __builtin_amdgcn_mfma_f32_16x16x32_bf16(a3, Bi[kt], Ci[3], 0,0,0);
      } else {
        Cn[0] = __builtin_amdgcn_mfma_f32_16x16x32_bf16(a0, Bn[kt-4], Cn[0], 0,0,0);
        Cn[1] = __builtin_amdgcn_mfma_f32_16x16x32_bf16(a1, Bn[kt-4], Cn[1], 0,0,0);
        Cn[2] = __builtin_amdgcn_mfma_f32_16x16x32_bf16(a2, Bn[kt-4], Cn[2], 0,0,0);
        Cn[3] = __builtin_amdgcn_mfma_f32_16x16x32_bf16(a3, Bn[kt-4], Cn[3], 0,0,0);
      }
    }
    __syncthreads();   // bar B: all As reads done

    // commit x_{t+1} (As x-region free now), then prefetch x_{t+2}
    if (step + 1 < T_) {
      uint32* xp = (uint32*)(As + ss*264 + cc);
      #pragma unroll
      for (int u=0;u<8;++u) xp[u] = xw[u];
      if (step + 2 < T_ && qq < NSEQ) {
        int tn = dir ? (T_-3-step) : (step+2);
        const uint32* gp = (const uint32*)(x4raw + ((size_t)qq*T_ + tn)*H_ + cc);
        #pragma unroll
        for (int u=0;u<8;++u) xw[u] = gp[u];
      }
    }

    // gates + h update
    #pragma unroll
    for (int rt=0;rt<4;++rt){
      #pragma unroll
      for (int rr=0;rr<4;++rr){
        float r_ = sigmoidf(Cr[rt][rr]);
        float z_ = sigmoidf(Cz[rt][rr]);
        float n_ = tanhfast(Ci[rt][rr] + r_*Cn[rt][rr]);
        float hn = (1.f - z_)*n_ + z_*hreg[rt*4+rr];
        hreg[rt*4+rr] = hn;
        int row = rt*16 + (lane>>4)*4 + rr;
        As[(size_t)row*264 + 128 + j0 + c15] = (unsigned short)f2bf_bits(hn);
        hs[row*132 + j0 + c15] = hn;
      }
    }
    __syncthreads();   // bar C: h_t + x_{t+1} staged

    // projections
    if (qq < NSEQ) {
      const f32x4* hrow = (const f32x4*)(hs + ss*132 + cc);
      f32x4 h0=hrow[0], h1=hrow[1], h2=hrow[2], h3=hrow[3];
      size_t obase = ((size_t)qq*T_ + t)*2;
      if (dir == 0) {
        const f32x4* pw0 = (const f32x4*)(pws + cc);
        const f32x4* pw1 = (const f32x4*)(pws + H_ + cc);
        const f32x4* ew0 = (const f32x4*)(ews + cc);
        const f32x4* ew1 = (const f32x4*)(ews + 2*H_ + cc);
        float p0 = dot4(pw0[0],h0)+dot4(pw0[1],h1)+dot4(pw0[2],h2)+dot4(pw0[3],h3);
        float p1 = dot4(pw1[0],h0)+dot4(pw1[1],h1)+dot4(pw1[2],h2)+dot4(pw1[3],h3);
        float e0 = dot4(ew0[0],h0)+dot4(ew0[1],h1)+dot4(ew0[2],h2)+dot4(ew0[3],h3);
        float e1 = dot4(ew1[0],h0)+dot4(ew1[1],h1)+dot4(ew1[2],h2)+dot4(ew1[3],h3);
        #pragma unroll
        for (int m=1;m<8;m<<=1){
          p0 += __shfl_xor(p0,m); p1 += __shfl_xor(p1,m);
          e0 += __shfl_xor(e0,m); e1 += __shfl_xor(e1,m);
        }
        if ((tid & 7) == 0) {
          out_prior[obase]   = p0 + pb0;
          out_prior[obase+1] = p1 + pb1;
          atomicAdd(&out_enc[obase],   e0);
          atomicAdd(&out_enc[obase+1], e1);
        }
      } else {
        const f32x4* ew0 = (const f32x4*)(ews + H_ + cc);
        const f32x4* ew1 = (const f32x4*)(ews + 2*H_ + H_ + cc);
        float e0 = dot4(ew0[0],h0)+dot4(ew0[1],h1)+dot4(ew0[2],h2)+dot4(ew0[3],h3);
        float e1 = dot4(ew1[0],h0)+dot4(ew1[1],h1)+dot4(ew1[2],h2)+dot4(ew1[3],h3);
        #pragma unroll
        for (int m=1;m<8;m<<=1){
          e0 += __shfl_xor(e0,m); e1 += __shfl_xor(e1,m);
        }
        if ((tid & 7) == 0) {
          atomicAdd(&out_enc[obase],   e0 + eb0);
          atomicAdd(&out_enc[obase+1], e1 + eb1);
        }
      }
    }
  }

  if (dir == 0) {
    __syncthreads();
    for (int idx = tid; idx < 64*H_; idx += 512) {
      int s = idx >> 7, c = idx & 127;
      int q = seq0 + s;
      if (q < NSEQ) out_hT[(size_t)q*H_ + c] = hs[s*132 + c];
    }
  }
}

// diagnostic: report ws_size via absmax
__global__ void ws_report(float* out, float v){ out[0] = v; }

// ================= host launcher =================
extern "C" void kernel_launch(void* const* d_in, const int* in_sizes, int n_in,
                              void* d_out, int out_size, void* d_ws, size_t ws_size,
                              hipStream_t stream)
{
  (void)in_sizes; (void)n_in; (void)out_size;
  const float* inputs = (const float*)d_in[0];
  const float* m1_w1 = (const float*)d_in[3];  const float* m1_b1 = (const float*)d_in[4];
  const float* m1_w2 = (const float*)d_in[5];  const float* m1_b2 = (const float*)d_in[6];
  const float* m1_g  = (const float*)d_in[7];  const float* m1_bt = (const float*)d_in[8];
  const float* m2_w1 = (const float*)d_in[9];  const float* m2_b1 = (const float*)d_in[10];
  const float* m2_w2 = (const float*)d_in[11]; const float* m2_b2 = (const float*)d_in[12];
  const float* m2_g  = (const float*)d_in[13]; const float* m2_bt = (const float*)d_in[14];
  const float* m3_w1 = (const float*)d_in[15]; const float* m3_b1 = (const float*)d_in[16];
  const float* m3_w2 = (const float*)d_in[17]; const float* m3_b2 = (const float*)d_in[18];
  const float* m3_g  = (const float*)d_in[19]; const float* m3_bt = (const float*)d_in[20];
  const float* m4_w1 = (const float*)d_in[21]; const float* m4_b1 = (const float*)d_in[22];
  const float* m4_w2 = (const float*)d_in[23]; const float* m4_b2 = (const float*)d_in[24];
  const float* m4_g  = (const float*)d_in[25]; const float* m4_bt = (const float*)d_in[26];
  const float* gf_wih = (const float*)d_in[27]; const float* gf_whh = (const float*)d_in[28];
  const float* gf_bih = (const float*)d_in[29]; const float* gf_bhh = (const float*)d_in[30];
  const float* gr_wih = (const float*)d_in[31]; const float* gr_whh = (const float*)d_in[32];
  const float* gr_bih = (const float*)d_in[33]; const float* gr_bhh = (const float*)d_in[34];
  const float* pw = (const float*)d_in[35]; const float* pb = (const float*)d_in[36];
  const float* ew = (const float*)d_in[37]; const float* eb = (const float*)d_in[38];

  float* out       = (float*)d_out;
  float* out_prior = out;
  float* out_enc   = out + (size_t)RE*2;
  float* out_hT    = out + (size_t)RE*4;

  size_t x4elems = (size_t)RE*H_;
  size_t nodeElems = (size_t)RN*H_;
  unsigned short* x4pre = (unsigned short*)d_ws;
  float* nodeA = (float*)(x4pre + x4elems);           // MLP1 pre-BN
  float* nodeB = nodeA + nodeElems;                   // e2n accumulator
  float* nodeC = nodeB + nodeElems;                   // MLP3 pre-BN
  float* stats = nodeC + nodeElems;                   // 1024 floats
  float* aff   = stats + 1024;                        // aff2, aff4
  unsigned short* wbf  = (unsigned short*)(aff + 512);// 114688 bf16
  unsigned short* x1bf = wbf + 114688;                // RN*H bf16
  unsigned short* x3bf = (unsigned short*)nodeA;      // aliases nodeA (dead after BN1)
  size_t need = (size_t)((char*)(x1bf + nodeElems) - (char*)d_ws);
  if (ws_size < need) {
    ws_report<<<1, 1, 0, stream>>>(out_prior, (float)ws_size);
    return;
  }

  (void)hipMemsetAsync(stats, 0, 1024*sizeof(float), stream);
  (void)hipMemsetAsync(nodeB, 0, nodeElems*sizeof(float), stream);
  (void)hipMemsetAsync(out_enc, 0, (size_t)RE*2*sizeof(float), stream);

  prep_weights<<<448, 256, 0, stream>>>(m2_w1, m2_w2, m4_w1, m4_w2, wbf);

  // MLP1 -> nodeA (pre-BN); BN1 -> x1bf (bf16)
  mlp_fused<0, FIN><<<RN/64, 256, 0, stream>>>(inputs, m1_w1, m1_b1, m1_w2, m1_b2, nodeA);
  stats_kernel<<<512, 128, 0, stream>>>(nodeA, RN, stats + 0);
  norm_to_bf16<<<512, 128, 0, stream>>>(nodeA, RN, stats + 0, m1_g, m1_bt, x1bf);

  // MLP2 (MFMA, no x2 store): BN2 stats + scatter raw x2 into nodeB
  mlp2_scatter<<<RE/64, 256, 0, stream>>>(x1bf, wbf, m2_b1, m2_b2, nodeB, stats + 256);
  finalize_aff<<<1, 128, 0, stream>>>(stats + 256, m2_g, m2_bt, aff + 0, RE);
  e2n_finalize<<<(RN*H_ + 255)/256, 256, 0, stream>>>(nodeB, aff + 0);

  // MLP3 -> nodeC (pre-BN); BN3 -> x3bf (bf16, aliases dead nodeA)
  mlp_fused<2, H_><<<RN/64, 256, 0, stream>>>(nodeB, m3_w1, m3_b1, m3_w2, m3_b2, nodeC);
  stats_kernel<<<512, 128, 0, stream>>>(nodeC, RN, stats + 512);
  norm_to_bf16<<<512, 128, 0, stream>>>(nodeC, RN, stats + 512, m3_g, m3_bt, x3bf);

  // MLP2-recompute + MLP4 (MFMA) -> x4pre bf16 + BN4 stats
  mlp24_fused<<<RE/64, 256, 0, stream>>>(x1bf, x3bf, aff + 0, wbf,
      m2_b1, m2_b2, m4_b1, m4_b2, x4pre, stats + 768);
  finalize_aff<<<1, 128, 0, stream>>>(stats + 768, m4_g, m4_bt, aff + 256, RE);

  // bidirectional GRU (MFMA, BN4 folded into weights) + fused projections
  gru_kernel<<<2*NB_GRU, 512, 0, stream>>>(x4pre, aff + 256,
      gf_wih, gf_whh, gf_bih, gf_bhh,
      gr_wih, gr_whh, gr_bih, gr_bhh,
      pw, pb, ew, eb, out_prior, out_enc, out_hT);
}

// Round 15
// 1916.474 us; speedup vs baseline: 1.2970x; 1.0195x over previous
//
#include <hip/hip_runtime.h>
#include <math.h>

typedef float f32x4 __attribute__((ext_vector_type(4)));
typedef short bf16x8 __attribute__((ext_vector_type(8)));
typedef unsigned int uint32;
#define DEV static __device__ __forceinline__

constexpr int B_ = 8, N_ = 30, T_ = 100, FIN = 4, H_ = 128;
constexpr int E_ = N_*(N_-1);          // 870
constexpr int NSEQ = B_*E_;            // 6960
constexpr int RN = B_*N_*T_;           // 24000 node rows
constexpr int RE = B_*E_*T_;           // 696000 edge rows
constexpr int ET = E_*T_;              // 87000
constexpr int NB_GRU = (NSEQ + 63)/64; // 109

DEV float eluf(float x){ return x > 0.f ? x : __expf(x) - 1.f; }
DEV float sigmoidf(float x){ return 1.f/(1.f + __expf(-x)); }
DEV float tanhfast(float x){
  float cx = fminf(fmaxf(x, -20.f), 20.f);
  float e = __expf(2.f*cx);
  return (e - 1.f)/(e + 1.f);
}
DEV float dot4(f32x4 a, f32x4 b){ return a[0]*b[0] + a[1]*b[1] + a[2]*b[2] + a[3]*b[3]; }

DEV float bf2f(unsigned short u){ return __uint_as_float(((uint32)u) << 16); }
DEV uint32 f2bf_bits(float f){ uint32 b = __float_as_uint(f); return (b + 0x7FFFu + ((b >> 16) & 1u)) >> 16; }
DEV uint32 pack2(float lo, float hi){ return f2bf_bits(lo) | (f2bf_bits(hi) << 16); }

// load 8 consecutive floats, round to 8 bf16
DEV bf16x8 cvt8(const float* __restrict__ p){
  f32x4 a = *(const f32x4*)p;
  f32x4 b = *(const f32x4*)(p+4);
  bf16x8 r;
  r[0]=(short)f2bf_bits(a[0]); r[1]=(short)f2bf_bits(a[1]);
  r[2]=(short)f2bf_bits(a[2]); r[3]=(short)f2bf_bits(a[3]);
  r[4]=(short)f2bf_bits(b[0]); r[5]=(short)f2bf_bits(b[1]);
  r[6]=(short)f2bf_bits(b[2]); r[7]=(short)f2bf_bits(b[3]);
  return r;
}
// same but element-wise scaled (BN fold)
DEV bf16x8 cvt8s(const float* __restrict__ p, const float* __restrict__ sc){
  bf16x8 r;
  #pragma unroll
  for (int e=0;e<8;++e) r[e] = (short)f2bf_bits(p[e]*sc[e]);
  return r;
}

// decompose edge row -> b, t, sender node, receiver node
DEV void edge_decomp(int row, int& b, int& t, int& sn, int& ir)
{
  b = row / ET;
  int rem = row - b*ET;
  int e   = rem / T_;
  t = rem - e*T_;
  ir = e / (N_-1);
  int j = e - ir*(N_-1);
  sn = j + (j >= ir ? 1 : 0);
}

// bijective XCD swizzle (m204)
DEV int xcd_swizzle(int orig, int nwg)
{
  int q = nwg >> 3, r = nwg & 7;
  int xcd = orig & 7, j = orig >> 3;
  return (xcd < r ? xcd*(q+1) : r*(q+1) + (xcd-r)*q) + j;
}

// ================= weight prep: fp32 -> bf16 (w21|w22|w41|w42) =================
__global__ __launch_bounds__(256)
void prep_weights(const float* __restrict__ w21, const float* __restrict__ w22,
                  const float* __restrict__ w41, const float* __restrict__ w42,
                  unsigned short* __restrict__ wbf)
{
  int idx = blockIdx.x*256 + threadIdx.x;
  if (idx >= 114688) return;
  float v;
  if (idx < 32768)      v = w21[idx];
  else if (idx < 49152) v = w22[idx - 32768];
  else if (idx < 98304) v = w41[idx - 49152];
  else                  v = w42[idx - 98304];
  wbf[idx] = (unsigned short)f2bf_bits(v);
}

// ========= fused 2-layer MLP (node-sized, fp32 out) + fused BN stats =========
// MODE 0: MLP1 (src = inputs RN x 4).
// MODE 2: MLP3 (src = raw e2n accumulator; applies (v*sc2 + 29*sh2)/30 on load).
template<int MODE, int DIN>
__global__ __launch_bounds__(256)
void mlp_fused(const float* __restrict__ src, const float* __restrict__ aff2,
               const float* __restrict__ w1, const float* __restrict__ b1,
               const float* __restrict__ w2, const float* __restrict__ b2,
               float* __restrict__ out, float* __restrict__ stats)
{
  constexpr int KC  = (DIN < 32) ? DIN : 32;
  constexpr int NCH = DIN / KC;
  __shared__ float As[KC][68];
  __shared__ float Ws[32][132];     // also reused as stats-reduction scratch (4224 f32)
  __shared__ float Hs[128][68];

  const int tid  = threadIdx.x;
  const int row0 = blockIdx.x * 64;
  const int tx = tid & 15, ty = tid >> 4;
  const int c0 = tx*8, r0 = ty*4;

  float acc[4][8];
  #pragma unroll
  for (int j=0;j<4;++j){
    #pragma unroll
    for (int i=0;i<8;++i) acc[j][i]=0.f;
  }

  for (int ch = 0; ch < NCH; ++ch) {
    for (int idx = tid; idx < 64*KC; idx += 256) {
      int r = idx / KC, k = idx % KC;
      float v = src[(size_t)(row0 + r)*DIN + ch*KC + k];
      if constexpr (MODE == 2) {
        int c = ch*KC + k;
        v = (v*aff2[c] + (float)(N_-1)*aff2[128+c]) * (1.f/(float)N_);
      }
      As[k][r] = v;
    }
    for (int idx = tid; idx < 128*KC; idx += 256) {
      int o = idx / KC, k = idx % KC;
      Ws[k][o] = w1[o*DIN + ch*KC + k];
    }
    __syncthreads();
    #pragma unroll
    for (int k = 0; k < KC; ++k) {
      f32x4 a  = *(const f32x4*)&As[k][r0];
      f32x4 wA = *(const f32x4*)&Ws[k][c0];
      f32x4 wB = *(const f32x4*)&Ws[k][c0+4];
      #pragma unroll
      for (int j=0;j<4;++j){
        #pragma unroll
        for (int i=0;i<4;++i){
          acc[j][i]   += a[j]*wA[i];
          acc[j][4+i] += a[j]*wB[i];
        }
      }
    }
    __syncthreads();
  }
  {
    #pragma unroll
    for (int i=0;i<8;++i){
      float bb = b1[c0+i];
      #pragma unroll
      for (int j=0;j<4;++j)
        Hs[c0+i][r0+j] = eluf(acc[j][i] + bb);
    }
  }
  __syncthreads();

  #pragma unroll
  for (int j=0;j<4;++j){
    #pragma unroll
    for (int i=0;i<8;++i) acc[j][i]=0.f;
  }

  for (int ch = 0; ch < 4; ++ch) {
    for (int idx = tid; idx < 128*32; idx += 256) {
      int o = idx >> 5, k = idx & 31;
      Ws[k][o] = w2[o*H_ + ch*32 + k];
    }
    __syncthreads();
    #pragma unroll
    for (int k = 0; k < 32; ++k) {
      f32x4 a  = *(const f32x4*)&Hs[ch*32 + k][r0];
      f32x4 wA = *(const f32x4*)&Ws[k][c0];
      f32x4 wB = *(const f32x4*)&Ws[k][c0+4];
      #pragma unroll
      for (int j=0;j<4;++j){
        #pragma unroll
        for (int i=0;i<4;++i){
          acc[j][i]   += a[j]*wA[i];
          acc[j][4+i] += a[j]*wB[i];
        }
      }
    }
    __syncthreads();
  }

  // epilogue: write out + accumulate BN stats (partials reduced via Ws scratch)
  float s1[8], s2[8];
  #pragma unroll
  for (int i=0;i<8;++i){ s1[i]=0.f; s2[i]=0.f; }
  {
    #pragma unroll
    for (int j=0;j<4;++j){
      size_t base = (size_t)(row0 + r0 + j)*H_ + c0;
      #pragma unroll
      for (int i=0;i<8;++i){
        float v = eluf(acc[j][i] + b2[c0+i]);
        out[base+i] = v;
        s1[i] += v; s2[i] += v*v;
      }
    }
  }
  __syncthreads();                 // Ws dead -> reuse as reduction scratch
  float* red = &Ws[0][0];          // need 4096 floats, have 4224
  #pragma unroll
  for (int i=0;i<8;++i){
    red[(c0+i)*16 + ty]        = s1[i];
    red[2048 + (c0+i)*16 + ty] = s2[i];
  }
  __syncthreads();
  if (tid < 128) {
    float s=0.f, q=0.f;
    #pragma unroll
    for (int u=0;u<16;++u){ s += red[tid*16+u]; q += red[2048 + tid*16+u]; }
    atomicAdd(&stats[tid], s);
    atomicAdd(&stats[128+tid], q);
  }
}

// ================= BN apply -> bf16 buffer =================
__global__ __launch_bounds__(128)
void norm_to_bf16(const float* __restrict__ buf, int rows, const float* __restrict__ sums,
                  const float* __restrict__ g, const float* __restrict__ bt,
                  unsigned short* __restrict__ outbf)
{
  int c = threadIdx.x;
  float inv = 1.f/(float)rows;
  float mu  = sums[c]*inv;
  float var = sums[H_+c]*inv - mu*mu;
  float sc  = rsqrtf(var + 1e-5f)*g[c];
  float sh  = bt[c] - mu*sc;
  for (int r = blockIdx.x; r < rows; r += gridDim.x) {
    size_t idx = (size_t)r*H_ + c;
    outbf[idx] = (unsigned short)f2bf_bits(buf[idx]*sc + sh);
  }
}

// ================= MLP2 via MFMA (wave = 32 cols x 64 rows, B in regs) ============
__global__ __launch_bounds__(256, 2)
void mlp2_scatter(const unsigned short* __restrict__ x1bf,
                  const unsigned short* __restrict__ wbf,
                  const float* __restrict__ b21, const float* __restrict__ b22,
                  float* __restrict__ nodeB, float* __restrict__ stats2)
{
  __shared__ int srow[64], rrow[64];
  __shared__ __align__(16) char pool[17408];     // bufH [64*136 ushort]; red aliases
  unsigned short* bufH = (unsigned short*)pool;
  float* red = (float*)pool;                     // [2][128][4]

  const int tid  = threadIdx.x;
  const int bid  = xcd_swizzle(blockIdx.x, gridDim.x);
  const int row0 = bid * 64;
  if (tid < 64) {
    int b,t,sn,ir; edge_decomp(row0 + tid, b, t, sn, ir);
    srow[tid] = (b*N_ + sn)*T_ + t;
    rrow[tid] = (b*N_ + ir)*T_ + t;
  }
  __syncthreads();

  const int lane = tid & 63;
  const int wv   = tid >> 6;          // 0..3
  const int c15  = lane & 15;
  const int k8   = (lane >> 4) * 8;
  const int g4   = (lane >> 4);       // C-row group
  const int colb = wv * 32;
  const unsigned short* W21 = wbf;
  const unsigned short* W22 = wbf + 32768;

  int sA[4], rA[4];
  #pragma unroll
  for (int rt=0;rt<4;++rt){ sA[rt] = srow[rt*16 + c15]; rA[rt] = rrow[rt*16 + c15]; }

  f32x4 C[2][4];

  // ---- P1: [x1 snd | x1 rcv] (K=256) ----
  #pragma unroll
  for (int ci=0;ci<2;++ci){
    float bb = b21[colb + ci*16 + c15];
    #pragma unroll
    for (int rt=0;rt<4;++rt) C[ci][rt] = (f32x4){bb,bb,bb,bb};
  }
  {
    bf16x8 Bf[2][8];
    #pragma unroll
    for (int ci=0;ci<2;++ci){
      #pragma unroll
      for (int kc=0;kc<8;++kc)
        Bf[ci][kc] = *(const bf16x8*)&W21[(size_t)(colb+ci*16+c15)*256 + kc*32 + k8];
    }
    #pragma unroll
    for (int kc=0;kc<8;++kc){
      bf16x8 A[4];
      #pragma unroll
      for (int rt=0;rt<4;++rt){
        int nrow = (kc<4) ? sA[rt] : rA[rt];
        A[rt] = *(const bf16x8*)&x1bf[(size_t)nrow*H_ + (kc&3)*32 + k8];
      }
      #pragma unroll
      for (int ci=0;ci<2;++ci){
        #pragma unroll
        for (int rt=0;rt<4;++rt)
          C[ci][rt] = __builtin_amdgcn_mfma_f32_16x16x32_bf16(A[rt], Bf[ci][kc], C[ci][rt], 0,0,0);
      }
    }
  }
  #pragma unroll
  for (int ci=0;ci<2;++ci){
    #pragma unroll
    for (int rt=0;rt<4;++rt){
      #pragma unroll
      for (int rr=0;rr<4;++rr){
        int row = rt*16 + g4*4 + rr;
        bufH[row*136 + colb + ci*16 + c15] = (unsigned short)f2bf_bits(eluf(C[ci][rt][rr]));
      }
    }
  }
  __syncthreads();

  // ---- P2: H1 (K=128) -> x2 raw ----
  #pragma unroll
  for (int ci=0;ci<2;++ci){
    float bb = b22[colb + ci*16 + c15];
    #pragma unroll
    for (int rt=0;rt<4;++rt) C[ci][rt] = (f32x4){bb,bb,bb,bb};
  }
  {
    bf16x8 Bf[2][4];
    #pragma unroll
    for (int ci=0;ci<2;++ci){
      #pragma unroll
      for (int kc=0;kc<4;++kc)
        Bf[ci][kc] = *(const bf16x8*)&W22[(size_t)(colb+ci*16+c15)*128 + kc*32 + k8];
    }
    #pragma unroll
    for (int kc=0;kc<4;++kc){
      bf16x8 A[4];
      #pragma unroll
      for (int rt=0;rt<4;++rt)
        A[rt] = *(const bf16x8*)&bufH[(rt*16+c15)*136 + kc*32 + k8];
      #pragma unroll
      for (int ci=0;ci<2;++ci){
        #pragma unroll
        for (int rt=0;rt<4;++rt)
          C[ci][rt] = __builtin_amdgcn_mfma_f32_16x16x32_bf16(A[rt], Bf[ci][kc], C[ci][rt], 0,0,0);
      }
    }
  }

  // ---- epilogue: elu, scatter to nodeB, BN2 stats ----
  float s1l[2], s2l[2];
  #pragma unroll
  for (int ci=0;ci<2;++ci){ s1l[ci]=0.f; s2l[ci]=0.f; }
  #pragma unroll
  for (int ci=0;ci<2;++ci){
    int col = colb + ci*16 + c15;
    #pragma unroll
    for (int rt=0;rt<4;++rt){
      #pragma unroll
      for (int rr=0;rr<4;++rr){
        int row = rt*16 + g4*4 + rr;
        float v = eluf(C[ci][rt][rr]);
        atomicAdd(&nodeB[(size_t)rrow[row]*H_ + col], v);
        s1l[ci] += v; s2l[ci] += v*v;
      }
    }
  }
  __syncthreads();            // bufH dead -> reuse as red
  #pragma unroll
  for (int ci=0;ci<2;++ci){
    int col = colb + ci*16 + c15;
    red[col*4 + g4]       = s1l[ci];
    red[512 + col*4 + g4] = s2l[ci];
  }
  __syncthreads();
  if (tid < 128) {
    float s=0.f, q=0.f;
    #pragma unroll
    for (int u=0;u<4;++u){ s += red[tid*4+u]; q += red[512 + tid*4+u]; }
    atomicAdd(&stats2[tid], s);
    atomicAdd(&stats2[128+tid], q);
  }
}

// ================= MLP2-recompute + MLP4 (wave = 32 cols x 64 rows) ==============
__global__ __launch_bounds__(256, 2)
void mlp24_fused(const unsigned short* __restrict__ x1bf, const unsigned short* __restrict__ x3bf,
                 const float* __restrict__ aff2, const unsigned short* __restrict__ wbf,
                 const float* __restrict__ b21, const float* __restrict__ b22,
                 const float* __restrict__ b41, const float* __restrict__ b42,
                 unsigned short* __restrict__ x4pre, float* __restrict__ stats4)
{
  __shared__ int srow[64], rrow[64];
  __shared__ __align__(16) char pool[34816];     // bufH | bufX ; red aliases bufH
  unsigned short* bufH = (unsigned short*)pool;
  unsigned short* bufX = (unsigned short*)(pool + 17408);
  float* red = (float*)pool;

  const int tid  = threadIdx.x;
  const int bid  = xcd_swizzle(blockIdx.x, gridDim.x);
  const int row0 = bid * 64;
  if (tid < 64) {
    int b,t,sn,ir; edge_decomp(row0 + tid, b, t, sn, ir);
    srow[tid] = (b*N_ + sn)*T_ + t;
    rrow[tid] = (b*N_ + ir)*T_ + t;
  }
  __syncthreads();

  const int lane = tid & 63;
  const int wv   = tid >> 6;
  const int c15  = lane & 15;
  const int k8   = (lane >> 4) * 8;
  const int g4   = (lane >> 4);
  const int colb = wv * 32;
  const unsigned short* W21 = wbf;
  const unsigned short* W22 = wbf + 32768;
  const unsigned short* W41 = wbf + 49152;
  const unsigned short* W42 = wbf + 98304;

  int sA[4], rA[4];
  #pragma unroll
  for (int rt=0;rt<4;++rt){ sA[rt] = srow[rt*16 + c15]; rA[rt] = rrow[rt*16 + c15]; }

  f32x4 C[2][4];

  // ---------- P1: MLP2 L1 (K=256) -> bufH ----------
  #pragma unroll
  for (int ci=0;ci<2;++ci){
    float bb = b21[colb + ci*16 + c15];
    #pragma unroll
    for (int rt=0;rt<4;++rt) C[ci][rt] = (f32x4){bb,bb,bb,bb};
  }
  {
    bf16x8 Bf[2][8];
    #pragma unroll
    for (int ci=0;ci<2;++ci){
      #pragma unroll
      for (int kc=0;kc<8;++kc)
        Bf[ci][kc] = *(const bf16x8*)&W21[(size_t)(colb+ci*16+c15)*256 + kc*32 + k8];
    }
    #pragma unroll
    for (int kc=0;kc<8;++kc){
      bf16x8 A[4];
      #pragma unroll
      for (int rt=0;rt<4;++rt){
        int nrow = (kc<4) ? sA[rt] : rA[rt];
        A[rt] = *(const bf16x8*)&x1bf[(size_t)nrow*H_ + (kc&3)*32 + k8];
      }
      #pragma unroll
      for (int ci=0;ci<2;++ci){
        #pragma unroll
        for (int rt=0;rt<4;++rt)
          C[ci][rt] = __builtin_amdgcn_mfma_f32_16x16x32_bf16(A[rt], Bf[ci][kc], C[ci][rt], 0,0,0);
      }
    }
  }
  #pragma unroll
  for (int ci=0;ci<2;++ci){
    #pragma unroll
    for (int rt=0;rt<4;++rt){
      #pragma unroll
      for (int rr=0;rr<4;++rr){
        int row = rt*16 + g4*4 + rr;
        bufH[row*136 + colb + ci*16 + c15] = (unsigned short)f2bf_bits(eluf(C[ci][rt][rr]));
      }
    }
  }
  __syncthreads();

  // ---------- P2: MLP2 L2 (K=128) -> bufX = elu()*aff2 ----------
  #pragma unroll
  for (int ci=0;ci<2;++ci){
    float bb = b22[colb + ci*16 + c15];
    #pragma unroll
    for (int rt=0;rt<4;++rt) C[ci][rt] = (f32x4){bb,bb,bb,bb};
  }
  {
    bf16x8 Bf[2][4];
    #pragma unroll
    for (int ci=0;ci<2;++ci){
      #pragma unroll
      for (int kc=0;kc<4;++kc)
        Bf[ci][kc] = *(const bf16x8*)&W22[(size_t)(colb+ci*16+c15)*128 + kc*32 + k8];
    }
    #pragma unroll
    for (int kc=0;kc<4;++kc){
      bf16x8 A[4];
      #pragma unroll
      for (int rt=0;rt<4;++rt)
        A[rt] = *(const bf16x8*)&bufH[(rt*16+c15)*136 + kc*32 + k8];
      #pragma unroll
      for (int ci=0;ci<2;++ci){
        #pragma unroll
        for (int rt=0;rt<4;++rt)
          C[ci][rt] = __builtin_amdgcn_mfma_f32_16x16x32_bf16(A[rt], Bf[ci][kc], C[ci][rt], 0,0,0);
      }
    }
  }
  #pragma unroll
  for (int ci=0;ci<2;++ci){
    int col = colb + ci*16 + c15;
    float sc = aff2[col], sh = aff2[128+col];
    #pragma unroll
    for (int rt=0;rt<4;++rt){
      #pragma unroll
      for (int rr=0;rr<4;++rr){
        int row = rt*16 + g4*4 + rr;
        bufX[row*136 + col] = (unsigned short)f2bf_bits(eluf(C[ci][rt][rr])*sc + sh);
      }
    }
  }
  __syncthreads();

  // ---------- P3: MLP4 L1 (K=384 = x3snd|x3rcv|X2) -> bufH ----------
  #pragma unroll
  for (int ci=0;ci<2;++ci){
    float bb = b41[colb + ci*16 + c15];
    #pragma unroll
    for (int rt=0;rt<4;++rt) C[ci][rt] = (f32x4){bb,bb,bb,bb};
  }
  {
    bf16x8 Bf[2][6];
    // batch 1: kc = 0..5
    #pragma unroll
    for (int ci=0;ci<2;++ci){
      #pragma unroll
      for (int kc=0;kc<6;++kc)
        Bf[ci][kc] = *(const bf16x8*)&W41[(size_t)(colb+ci*16+c15)*384 + kc*32 + k8];
    }
    #pragma unroll
    for (int kc=0;kc<6;++kc){
      bf16x8 A[4];
      #pragma unroll
      for (int rt=0;rt<4;++rt){
        if (kc < 4) A[rt] = *(const bf16x8*)&x3bf[(size_t)sA[rt]*H_ + kc*32 + k8];
        else        A[rt] = *(const bf16x8*)&x3bf[(size_t)rA[rt]*H_ + (kc-4)*32 + k8];
      }
      #pragma unroll
      for (int ci=0;ci<2;++ci){
        #pragma unroll
        for (int rt=0;rt<4;++rt)
          C[ci][rt] = __builtin_amdgcn_mfma_f32_16x16x32_bf16(A[rt], Bf[ci][kc], C[ci][rt], 0,0,0);
      }
    }
    // batch 2: kc = 6..11
    #pragma unroll
    for (int ci=0;ci<2;++ci){
      #pragma unroll
      for (int kc=0;kc<6;++kc)
        Bf[ci][kc] = *(const bf16x8*)&W41[(size_t)(colb+ci*16+c15)*384 + (kc+6)*32 + k8];
    }
    #pragma unroll
    for (int kc=6;kc<12;++kc){
      bf16x8 A[4];
      #pragma unroll
      for (int rt=0;rt<4;++rt){
        if (kc < 8) A[rt] = *(const bf16x8*)&x3bf[(size_t)rA[rt]*H_ + (kc-4)*32 + k8];
        else        A[rt] = *(const bf16x8*)&bufX[(rt*16+c15)*136 + (kc-8)*32 + k8];
      }
      #pragma unroll
      for (int ci=0;ci<2;++ci){
        #pragma unroll
        for (int rt=0;rt<4;++rt)
          C[ci][rt] = __builtin_amdgcn_mfma_f32_16x16x32_bf16(A[rt], Bf[ci][kc-6], C[ci][rt], 0,0,0);
      }
    }
  }
  __syncthreads();   // all bufX reads + prior bufH reads done before bufH overwrite
  #pragma unroll
  for (int ci=0;ci<2;++ci){
    #pragma unroll
    for (int rt=0;rt<4;++rt){
      #pragma unroll
      for (int rr=0;rr<4;++rr){
        int row = rt*16 + g4*4 + rr;
        bufH[row*136 + colb + ci*16 + c15] = (unsigned short)f2bf_bits(eluf(C[ci][rt][rr]));
      }
    }
  }
  __syncthreads();

  // ---------- P4: MLP4 L2 (K=128) -> x4pre bf16 + stats ----------
  #pragma unroll
  for (int ci=0;ci<2;++ci){
    float bb = b42[colb + ci*16 + c15];
    #pragma unroll
    for (int rt=0;rt<4;++rt) C[ci][rt] = (f32x4){bb,bb,bb,bb};
  }
  {
    bf16x8 Bf[2][4];
    #pragma unroll
    for (int ci=0;ci<2;++ci){
      #pragma unroll
      for (int kc=0;kc<4;++kc)
        Bf[ci][kc] = *(const bf16x8*)&W42[(size_t)(colb+ci*16+c15)*128 + kc*32 + k8];
    }
    #pragma unroll
    for (int kc=0;kc<4;++kc){
      bf16x8 A[4];
      #pragma unroll
      for (int rt=0;rt<4;++rt)
        A[rt] = *(const bf16x8*)&bufH[(rt*16+c15)*136 + kc*32 + k8];
      #pragma unroll
      for (int ci=0;ci<2;++ci){
        #pragma unroll
        for (int rt=0;rt<4;++rt)
          C[ci][rt] = __builtin_amdgcn_mfma_f32_16x16x32_bf16(A[rt], Bf[ci][kc], C[ci][rt], 0,0,0);
      }
    }
  }
  float s1l[2], s2l[2];
  #pragma unroll
  for (int ci=0;ci<2;++ci){ s1l[ci]=0.f; s2l[ci]=0.f; }
  #pragma unroll
  for (int ci=0;ci<2;++ci){
    int col = colb + ci*16 + c15;
    #pragma unroll
    for (int rt=0;rt<4;++rt){
      #pragma unroll
      for (int rr=0;rr<4;++rr){
        int row = rt*16 + g4*4 + rr;
        float v = eluf(C[ci][rt][rr]);
        x4pre[(size_t)(row0 + row)*H_ + col] = (unsigned short)f2bf_bits(v);
        s1l[ci] += v; s2l[ci] += v*v;
      }
    }
  }
  __syncthreads();            // bufH dead -> reuse as red
  #pragma unroll
  for (int ci=0;ci<2;++ci){
    int col = colb + ci*16 + c15;
    red[col*4 + g4]       = s1l[ci];
    red[512 + col*4 + g4] = s2l[ci];
  }
  __syncthreads();
  if (tid < 128) {
    float s=0.f, q=0.f;
    #pragma unroll
    for (int u=0;u<4;++u){ s += red[tid*4+u]; q += red[512 + tid*4+u]; }
    atomicAdd(&stats4[tid], s);
    atomicAdd(&stats4[128+tid], q);
  }
}

// ================= batchnorm helper =================
__global__ __launch_bounds__(128)
void finalize_aff(const float* __restrict__ sums, const float* __restrict__ g,
                  const float* __restrict__ bt, float* __restrict__ aff, int rows)
{
  int c = threadIdx.x;
  float inv = 1.f/(float)rows;
  float mu  = sums[c]*inv;
  float var = sums[H_+c]*inv - mu*mu;
  float sc  = rsqrtf(var + 1e-5f)*g[c];
  aff[c]      = sc;
  aff[H_ + c] = bt[c] - mu*sc;
}

// ===== bidirectional GRU via MFMA: 64 seqs/block, BN4 folded into weights =====
__global__ __launch_bounds__(512, 1)
void gru_kernel(const unsigned short* __restrict__ x4raw, const float* __restrict__ aff4,
                const float* __restrict__ wihf, const float* __restrict__ whhf,
                const float* __restrict__ bihf, const float* __restrict__ bhhf,
                const float* __restrict__ wihr, const float* __restrict__ whhr,
                const float* __restrict__ bihr, const float* __restrict__ bhhr,
                const float* __restrict__ pw, const float* __restrict__ pb,
                const float* __restrict__ ew, const float* __restrict__ eb,
                float* __restrict__ out_prior, float* __restrict__ out_enc,
                float* __restrict__ out_hT)
{
  __shared__ __align__(16) unsigned short As[64*264];
  __shared__ __align__(16) float hs[64*132];
  __shared__ float sc4[128], sh4[128];
  __shared__ float pws[256];     // pw 2x128
  __shared__ float ews[512];     // ew 2x256

  const int tid  = threadIdx.x;
  const int dir  = blockIdx.x / NB_GRU;
  const int blk  = blockIdx.x % NB_GRU;
  const int seq0 = blk * 64;
  const int lane = tid & 63;
  const int wv   = __builtin_amdgcn_readfirstlane(tid >> 6);
  const int j0   = wv * 16;
  const int c15  = lane & 15;
  const int k8g  = (lane >> 4) * 8;

  const float* wih = dir ? wihr : wihf;
  const float* whh = dir ? whhr : whhf;
  const float* bih = dir ? bihr : bihf;
  const float* bhh = dir ? bhhr : bhhf;

  for (int i = tid; i < 64*264; i += 512) As[i] = 0;
  for (int i = tid; i < 64*132; i += 512) hs[i] = 0.f;
  if (tid < 128) { sc4[tid] = aff4[tid]; sh4[tid] = aff4[128+tid]; }
  for (int i = tid; i < 256; i += 512) pws[i] = pw[i];
  for (int i = tid; i < 512; i += 512) ews[i] = ew[i];
  __syncthreads();

  bf16x8 Br[8], Bz[8], Bi[4], Bn[4];
  #pragma unroll
  for (int kt=0; kt<8; ++kt){
    if (kt < 4) {
      Br[kt] = cvt8s(wih + (size_t)(j0+c15)*H_ + kt*32 + k8g,     sc4 + kt*32 + k8g);
      Bz[kt] = cvt8s(wih + (size_t)(128+j0+c15)*H_ + kt*32 + k8g, sc4 + kt*32 + k8g);
    } else {
      Br[kt] = cvt8(whh + (size_t)(j0+c15)*H_ + (kt-4)*32 + k8g);
      Bz[kt] = cvt8(whh + (size_t)(128+j0+c15)*H_ + (kt-4)*32 + k8g);
    }
  }
  #pragma unroll
  for (int kt=0; kt<4; ++kt){
    Bi[kt] = cvt8s(wih + (size_t)(256+j0+c15)*H_ + kt*32 + k8g, sc4 + kt*32 + k8g);
    Bn[kt] = cvt8(whh + (size_t)(256+j0+c15)*H_ + kt*32 + k8g);
  }
  float dR=0.f, dZ=0.f, dI=0.f;
  for (int k=0; k<H_; ++k){
    float shk = sh4[k];
    dR += wih[(size_t)(j0+c15)*H_ + k]*shk;
    dZ += wih[(size_t)(128+j0+c15)*H_ + k]*shk;
    dI += wih[(size_t)(256+j0+c15)*H_ + k]*shk;
  }
  const float bR = bih[j0+c15]     + bhh[j0+c15]     + dR;
  const float bZ = bih[128+j0+c15] + bhh[128+j0+c15] + dZ;
  const float bI = bih[256+j0+c15] + dI;
  const float bN = bhh[256+j0+c15];
  const float pb0 = pb[0], pb1 = pb[1], eb0 = eb[0], eb1 = eb[1];

  float hreg[16];
  #pragma unroll
  for (int i=0;i<16;++i) hreg[i] = 0.f;

  const int ss = tid >> 3;
  const int cc = (tid & 7) * 16;
  const int qq = seq0 + ss;

  uint32 xw[8];
  {
    int t0 = dir ? (T_-1) : 0;
    if (qq < NSEQ) {
      const uint32* gp = (const uint32*)(x4raw + ((size_t)qq*T_ + t0)*H_ + cc);
      #pragma unroll
      for (int u=0;u<8;++u) xw[u] = gp[u];
    } else {
      #pragma unroll
      for (int u=0;u<8;++u) xw[u] = 0;
    }
    uint32* xp = (uint32*)(As + ss*264 + cc);
    #pragma unroll
    for (int u=0;u<8;++u) xp[u] = xw[u];
    if (qq < NSEQ) {
      int t1 = dir ? (T_-2) : 1;
      const uint32* gp = (const uint32*)(x4raw + ((size_t)qq*T_ + t1)*H_ + cc);
      #pragma unroll
      for (int u=0;u<8;++u) xw[u] = gp[u];
    }
  }
  __syncthreads();

  for (int step = 0; step < T_; ++step) {
    const int t = dir ? (T_-1-step) : step;

    f32x4 Cr[4], Cz[4], Ci[4], Cn[4];
    #pragma unroll
    for (int rt=0;rt<4;++rt){
      Cr[rt] = (f32x4){bR,bR,bR,bR};
      Cz[rt] = (f32x4){bZ,bZ,bZ,bZ};
      Ci[rt] = (f32x4){bI,bI,bI,bI};
      Cn[rt] = (f32x4){bN,bN,bN,bN};
    }
    #pragma unroll
    for (int kt=0; kt<8; ++kt){
      bf16x8 a0 = *(const bf16x8*)&As[(size_t)( 0+c15)*264 + kt*32 + k8g];
      bf16x8 a1 = *(const bf16x8*)&As[(size_t)(16+c15)*264 + kt*32 + k8g];
      bf16x8 a2 = *(const bf16x8*)&As[(size_t)(32+c15)*264 + kt*32 + k8g];
      bf16x8 a3 = *(const bf16x8*)&As[(size_t)(48+c15)*264 + kt*32 + k8g];
      Cr[0] = __builtin_amdgcn_mfma_f32_16x16x32_bf16(a0, Br[kt], Cr[0], 0,0,0);
      Cr[1] = __builtin_amdgcn_mfma_f32_16x16x32_bf16(a1, Br[kt], Cr[1], 0,0,0);
      Cr[2] = __builtin_amdgcn_mfma_f32_16x16x32_bf16(a2, Br[kt], Cr[2], 0,0,0);
      Cr[3] = __builtin_amdgcn_mfma_f32_16x16x32_bf16(a3, Br[kt], Cr[3], 0,0,0);
      Cz[0] = __builtin_amdgcn_mfma_f32_16x16x32_bf16(a0, Bz[kt], Cz[0], 0,0,0);
      Cz[1] = __builtin_amdgcn_mfma_f32_16x16x32_bf16(a1, Bz[kt], Cz[1], 0,0,0);
      Cz[2] = __builtin_amdgcn_mfma_f32_16x16x32_bf16(a2, Bz[kt], Cz[2], 0,0,0);
      Cz[3] = __builtin_amdgcn_mfma_f32_16x16x32_bf16(a3, Bz[kt], Cz[3], 0,0,0);
      if (kt < 4) {
        Ci[0] = __builtin_amdgcn_mfma_f32_16x16x32_bf16(a0, Bi[kt], Ci[0], 0,0,0);
        Ci[1] = __builtin_amdgcn_mfma_f32_16x16x32_bf16(a1, Bi[kt], Ci[1], 0,0,0);
        Ci[2] = __builtin_amdgcn_mfma_f32_16x16x32_bf16(a2, Bi[kt], Ci[2], 0,0,0);
        Ci[3] = __builtin_amdgcn_mfma_f32_16x16x32_bf16(a3, Bi[kt], Ci[3], 0,0,0);
      } else {
        Cn[0] = __builtin_amdgcn_mfma_f32_16x16x32_bf16(a0, Bn[kt-4], Cn[0], 0,0,0);
        Cn[1] = __builtin_amdgcn_mfma_f32_16x16x32_bf16(a1, Bn[kt-4], Cn[1], 0,0,0);
        Cn[2] = __builtin_amdgcn_mfma_f32_16x16x32_bf16(a2, Bn[kt-4], Cn[2], 0,0,0);
        Cn[3] = __builtin_amdgcn_mfma_f32_16x16x32_bf16(a3, Bn[kt-4], Cn[3], 0,0,0);
      }
    }
    __syncthreads();   // bar B: all As reads done

    if (step + 1 < T_) {
      uint32* xp = (uint32*)(As + ss*264 + cc);
      #pragma unroll
      for (int u=0;u<8;++u) xp[u] = xw[u];
      if (step + 2 < T_ && qq < NSEQ) {
        int tn = dir ? (T_-3-step) : (step+2);
        const uint32* gp = (const uint32*)(x4raw + ((size_t)qq*T_ + tn)*H_ + cc);
        #pragma unroll
        for (int u=0;u<8;++u) xw[u] = gp[u];
      }
    }

    #pragma unroll
    for (int rt=0;rt<4;++rt){
      #pragma unroll
      for (int rr=0;rr<4;++rr){
        float r_ = sigmoidf(Cr[rt][rr]);
        float z_ = sigmoidf(Cz[rt][rr]);
        float n_ = tanhfast(Ci[rt][rr] + r_*Cn[rt][rr]);
        float hn = (1.f - z_)*n_ + z_*hreg[rt*4+rr];
        hreg[rt*4+rr] = hn;
        int row = rt*16 + (lane>>4)*4 + rr;
        As[(size_t)row*264 + 128 + j0 + c15] = (unsigned short)f2bf_bits(hn);
        hs[row*132 + j0 + c15] = hn;
      }
    }
    __syncthreads();   // bar C: h_t + x_{t+1} staged

    if (qq < NSEQ) {
      const f32x4* hrow = (const f32x4*)(hs + ss*132 + cc);
      f32x4 h0=hrow[0], h1=hrow[1], h2=hrow[2], h3=hrow[3];
      size_t obase = ((size_t)qq*T_ + t)*2;
      if (dir == 0) {
        const f32x4* pw0 = (const f32x4*)(pws + cc);
        const f32x4* pw1 = (const f32x4*)(pws + H_ + cc);
        const f32x4* ew0 = (const f32x4*)(ews + cc);
        const f32x4* ew1 = (const f32x4*)(ews + 2*H_ + cc);
        float p0 = dot4(pw0[0],h0)+dot4(pw0[1],h1)+dot4(pw0[2],h2)+dot4(pw0[3],h3);
        float p1 = dot4(pw1[0],h0)+dot4(pw1[1],h1)+dot4(pw1[2],h2)+dot4(pw1[3],h3);
        float e0 = dot4(ew0[0],h0)+dot4(ew0[1],h1)+dot4(ew0[2],h2)+dot4(ew0[3],h3);
        float e1 = dot4(ew1[0],h0)+dot4(ew1[1],h1)+dot4(ew1[2],h2)+dot4(ew1[3],h3);
        #pragma unroll
        for (int m=1;m<8;m<<=1){
          p0 += __shfl_xor(p0,m); p1 += __shfl_xor(p1,m);
          e0 += __shfl_xor(e0,m); e1 += __shfl_xor(e1,m);
        }
        if ((tid & 7) == 0) {
          out_prior[obase]   = p0 + pb0;
          out_prior[obase+1] = p1 + pb1;
          atomicAdd(&out_enc[obase],   e0);
          atomicAdd(&out_enc[obase+1], e1);
        }
      } else {
        const f32x4* ew0 = (const f32x4*)(ews + H_ + cc);
        const f32x4* ew1 = (const f32x4*)(ews + 2*H_ + H_ + cc);
        float e0 = dot4(ew0[0],h0)+dot4(ew0[1],h1)+dot4(ew0[2],h2)+dot4(ew0[3],h3);
        float e1 = dot4(ew1[0],h0)+dot4(ew1[1],h1)+dot4(ew1[2],h2)+dot4(ew1[3],h3);
        #pragma unroll
        for (int m=1;m<8;m<<=1){
          e0 += __shfl_xor(e0,m); e1 += __shfl_xor(e1,m);
        }
        if ((tid & 7) == 0) {
          atomicAdd(&out_enc[obase],   e0 + eb0);
          atomicAdd(&out_enc[obase+1], e1 + eb1);
        }
      }
    }
  }

  if (dir == 0) {
    __syncthreads();
    for (int idx = tid; idx < 64*H_; idx += 512) {
      int s = idx >> 7, c = idx & 127;
      int q = seq0 + s;
      if (q < NSEQ) out_hT[(size_t)q*H_ + c] = hs[s*132 + c];
    }
  }
}

// diagnostic: report ws_size via absmax
__global__ void ws_report(float* out, float v){ out[0] = v; }

// ================= host launcher =================
extern "C" void kernel_launch(void* const* d_in, const int* in_sizes, int n_in,
                              void* d_out, int out_size, void* d_ws, size_t ws_size,
                              hipStream_t stream)
{
  (void)in_sizes; (void)n_in; (void)out_size;
  const float* inputs = (const float*)d_in[0];
  const float* m1_w1 = (const float*)d_in[3];  const float* m1_b1 = (const float*)d_in[4];
  const float* m1_w2 = (const float*)d_in[5];  const float* m1_b2 = (const float*)d_in[6];
  const float* m1_g  = (const float*)d_in[7];  const float* m1_bt = (const float*)d_in[8];
  const float* m2_w1 = (const float*)d_in[9];  const float* m2_b1 = (const float*)d_in[10];
  const float* m2_w2 = (const float*)d_in[11]; const float* m2_b2 = (const float*)d_in[12];
  const float* m2_g  = (const float*)d_in[13]; const float* m2_bt = (const float*)d_in[14];
  const float* m3_w1 = (const float*)d_in[15]; const float* m3_b1 = (const float*)d_in[16];
  const float* m3_w2 = (const float*)d_in[17]; const float* m3_b2 = (const float*)d_in[18];
  const float* m3_g  = (const float*)d_in[19]; const float* m3_bt = (const float*)d_in[20];
  const float* m4_w1 = (const float*)d_in[21]; const float* m4_b1 = (const float*)d_in[22];
  const float* m4_w2 = (const float*)d_in[23]; const float* m4_b2 = (const float*)d_in[24];
  const float* m4_g  = (const float*)d_in[25]; const float* m4_bt = (const float*)d_in[26];
  const float* gf_wih = (const float*)d_in[27]; const float* gf_whh = (const float*)d_in[28];
  const float* gf_bih = (const float*)d_in[29]; const float* gf_bhh = (const float*)d_in[30];
  const float* gr_wih = (const float*)d_in[31]; const float* gr_whh = (const float*)d_in[32];
  const float* gr_bih = (const float*)d_in[33]; const float* gr_bhh = (const float*)d_in[34];
  const float* pw = (const float*)d_in[35]; const float* pb = (const float*)d_in[36];
  const float* ew = (const float*)d_in[37]; const float* eb = (const float*)d_in[38];

  float* out       = (float*)d_out;
  float* out_prior = out;
  float* out_enc   = out + (size_t)RE*2;
  float* out_hT    = out + (size_t)RE*4;

  size_t x4elems = (size_t)RE*H_;
  size_t nodeElems = (size_t)RN*H_;
  unsigned short* x4pre = (unsigned short*)d_ws;
  float* nodeA = (float*)(x4pre + x4elems);           // MLP1 pre-BN
  float* nodeB = nodeA + nodeElems;                   // e2n accumulator (raw)
  float* nodeC = nodeB + nodeElems;                   // MLP3 pre-BN
  float* stats = nodeC + nodeElems;                   // 1024 floats
  float* aff   = stats + 1024;                        // aff2, aff4
  unsigned short* wbf  = (unsigned short*)(aff + 512);// 114688 bf16
  unsigned short* x1bf = wbf + 114688;                // RN*H bf16
  unsigned short* x3bf = (unsigned short*)nodeA;      // aliases nodeA (dead after BN1)
  size_t need = (size_t)((char*)(x1bf + nodeElems) - (char*)d_ws);
  if (ws_size < need) {
    ws_report<<<1, 1, 0, stream>>>(out_prior, (float)ws_size);
    return;
  }

  (void)hipMemsetAsync(stats, 0, 1024*sizeof(float), stream);
  (void)hipMemsetAsync(nodeB, 0, nodeElems*sizeof(float), stream);
  (void)hipMemsetAsync(out_enc, 0, (size_t)RE*2*sizeof(float), stream);

  prep_weights<<<448, 256, 0, stream>>>(m2_w1, m2_w2, m4_w1, m4_w2, wbf);

  // MLP1 -> nodeA (pre-BN) + BN1 stats fused; BN1 -> x1bf (bf16)
  mlp_fused<0, FIN><<<RN/64, 256, 0, stream>>>(inputs, nullptr,
      m1_w1, m1_b1, m1_w2, m1_b2, nodeA, stats + 0);
  norm_to_bf16<<<512, 128, 0, stream>>>(nodeA, RN, stats + 0, m1_g, m1_bt, x1bf);

  // MLP2 (MFMA, no x2 store): BN2 stats + scatter raw x2 into nodeB
  mlp2_scatter<<<RE/64, 256, 0, stream>>>(x1bf, wbf, m2_b1, m2_b2, nodeB, stats + 256);
  finalize_aff<<<1, 128, 0, stream>>>(stats + 256, m2_g, m2_bt, aff + 0, RE);

  // MLP3 -> nodeC (pre-BN) + BN3 stats fused; e2n affine fused into loader
  mlp_fused<2, H_><<<RN/64, 256, 0, stream>>>(nodeB, aff + 0,
      m3_w1, m3_b1, m3_w2, m3_b2, nodeC, stats + 512);
  norm_to_bf16<<<512, 128, 0, stream>>>(nodeC, RN, stats + 512, m3_g, m3_bt, x3bf);

  // MLP2-recompute + MLP4 (MFMA) -> x4pre bf16 + BN4 stats
  mlp24_fused<<<RE/64, 256, 0, stream>>>(x1bf, x3bf, aff + 0, wbf,
      m2_b1, m2_b2, m4_b1, m4_b2, x4pre, stats + 768);
  finalize_aff<<<1, 128, 0, stream>>>(stats + 768, m4_g, m4_bt, aff + 256, RE);

  // bidirectional GRU (MFMA, BN4 folded into weights) + fused projections
  gru_kernel<<<2*NB_GRU, 512, 0, stream>>>(x4pre, aff + 256,
      gf_wih, gf_whh, gf_bih, gf_bhh,
      gr_wih, gr_whh, gr_bih, gr_bhh,
      pw, pb, ew, eb, out_prior, out_enc, out_hT);
}